// Round 6
// baseline (1042.094 us; speedup 1.0000x reference)
//
#include <hip/hip_runtime.h>
#include <hip/hip_bf16.h>
#include <math.h>

#define TT 2080
#define DM 512
#define DI 2048
#define NH 8
#define DH 64
#define NMTOK 16
#define NLAYER 4
#define QKV_N 1536
#define ATT_SCALE 0.125f

typedef short bf16x8 __attribute__((ext_vector_type(8)));
typedef float f32x4 __attribute__((ext_vector_type(4)));
typedef unsigned short ushort_t;

__device__ __forceinline__ ushort_t f2bf(float f) {
  __hip_bfloat16 h = __float2bfloat16(f);
  return *reinterpret_cast<ushort_t*>(&h);
}
__device__ __forceinline__ float bfbits2f(unsigned int hi_bits) {
  return __uint_as_float(hi_bits);
}
__device__ __forceinline__ void unpack8(uint4 v, float* f) {
  f[0] = bfbits2f(v.x << 16); f[1] = bfbits2f(v.x & 0xffff0000u);
  f[2] = bfbits2f(v.y << 16); f[3] = bfbits2f(v.y & 0xffff0000u);
  f[4] = bfbits2f(v.z << 16); f[5] = bfbits2f(v.z & 0xffff0000u);
  f[6] = bfbits2f(v.w << 16); f[7] = bfbits2f(v.w & 0xffff0000u);
}
__device__ __forceinline__ unsigned int pack2(ushort_t lo, ushort_t hi) {
  return (unsigned int)lo | ((unsigned int)hi << 16);
}
// Barrier that drains LDS ops only — leaves global loads (vmcnt) in flight.
// __syncthreads() would emit s_waitcnt vmcnt(0) before s_barrier, draining
// our register prefetch every iteration (the ~500-900cyc serial cost).
__device__ __forceinline__ void barrier_lds() {
  asm volatile("s_waitcnt lgkmcnt(0)" ::: "memory");
  __builtin_amdgcn_s_barrier();
}

// ---------------- build w (fp32+bf16) and pos_emb (bf16) ------------------
__global__ __launch_bounds__(256) void k_build(const float* __restrict__ we,
                                               const float* __restrict__ mem,
                                               float* __restrict__ w,
                                               ushort_t* __restrict__ wb,
                                               ushort_t* __restrict__ posb) {
  int idx = blockIdx.x * 256 + threadIdx.x;
  if (idx >= TT * DM) return;
  int t = idx >> 9, d = idx & 511;
  float v;
  if (t < NMTOK) v = mem[t * DM + d];
  else if (t < NMTOK + 2048) v = we[(t - NMTOK) * DM + d];
  else v = mem[(t - (NMTOK + 2048)) * DM + d];
  w[idx] = v;
  wb[idx] = f2bf(v);
  float p = (float)(TT - 1 - t);
  int i2 = d & 255;
  float freq = 1.0f / powf(10000.f, ((float)(2 * i2)) / 512.f);
  float ang = p * freq;
  posb[idx] = f2bf((d < 256) ? sinf(ang) : cosf(ang));
}

// ---- batched transpose+cast of all 5 weight mats of one layer ------------
__global__ __launch_bounds__(256) void k_transpose_all(
    const float* __restrict__ Wqkv, const float* __restrict__ Wr,
    const float* __restrict__ Wo, const float* __restrict__ W1,
    const float* __restrict__ W2, ushort_t* __restrict__ dstAll, int l) {
  __shared__ float t[32][33];
  const int tid = threadIdx.x;
  int idx = blockIdx.x;
  const float* src;
  ushort_t* dst;
  int K, N, local;
  if (idx < 768)       { src = Wqkv + (size_t)l * 512 * 1536; dst = dstAll;          K = 512;  N = 1536; local = idx; }
  else if (idx < 1024) { src = Wr   + (size_t)l * 512 * 512;  dst = dstAll + 786432; K = 512;  N = 512;  local = idx - 768; }
  else if (idx < 1280) { src = Wo   + (size_t)l * 512 * 512;  dst = dstAll + 1048576; K = 512; N = 512;  local = idx - 1024; }
  else if (idx < 2304) { src = W1   + (size_t)l * 512 * 2048; dst = dstAll + 1310720; K = 512; N = 2048; local = idx - 1280; }
  else                 { src = W2   + (size_t)l * 2048 * 512; dst = dstAll + 2359296; K = 2048; N = 512; local = idx - 2304; }
  const int ntiles = N / 32;
  const int n0 = (local % ntiles) * 32, k0 = (local / ntiles) * 32;
#pragma unroll
  for (int p = 0; p < 4; ++p) {
    int row = (tid >> 5) + 8 * p, col = tid & 31;
    t[row][col] = src[(size_t)(k0 + row) * N + n0 + col];
  }
  __syncthreads();
#pragma unroll
  for (int p = 0; p < 4; ++p) {
    int n = (tid >> 5) + 8 * p, k = tid & 31;
    dst[(size_t)(n0 + n) * K + k0 + k] = f2bf(t[k][n]);
  }
}

// -------- bf16 MFMA GEMM 64x64, register-prefetch + lgkm-only barriers ----
// flags: 1=+bias, 2=relu, 4=bf16 output (else fp32)
__global__ __launch_bounds__(256) void k_gemm_mfma(const ushort_t* __restrict__ A,
                                                   const ushort_t* __restrict__ Bt,
                                                   const float* __restrict__ bias,
                                                   float* __restrict__ C,
                                                   ushort_t* __restrict__ Cb,
                                                   int M, int N, int K, int flags) {
  __shared__ short As[64][72];
  __shared__ short Bs[64][72];
  const int tid = threadIdx.x;
  const int m0 = blockIdx.y * 64, n0 = blockIdx.x * 64;
  const int lane = tid & 63, wv = tid >> 6;
  const int wm = (wv >> 1) * 32, wn = (wv & 1) * 32;
  const int lm = lane & 15, quad = lane >> 4;
  const int sr = tid >> 3, sc8 = (tid & 7) * 8;  // staging row / col chunk

  const uint4 zero4 = make_uint4(0, 0, 0, 0);
  f32x4 acc[2][2];
#pragma unroll
  for (int a = 0; a < 2; ++a)
#pragma unroll
    for (int b = 0; b < 2; ++b) acc[a][b] = (f32x4)(0.f);

  auto loadA = [&](int row, int k0) -> uint4 {
    return (m0 + row < M) ? *(const uint4*)&A[(size_t)(m0 + row) * K + k0 + sc8]
                          : zero4;
  };
  auto loadB = [&](int row, int k0) -> uint4 {
    return *(const uint4*)&Bt[(size_t)(n0 + row) * K + k0 + sc8];
  };

  uint4 a0c = loadA(sr, 0), a1c = loadA(sr + 32, 0);
  uint4 b0c = loadB(sr, 0), b1c = loadB(sr + 32, 0);

  for (int k0 = 0; k0 < K; k0 += 64) {
    const int kn = (k0 + 64 < K) ? k0 + 64 : k0;  // clamped reload on last iter
    uint4 a0n = loadA(sr, kn), a1n = loadA(sr + 32, kn);
    uint4 b0n = loadB(sr, kn), b1n = loadB(sr + 32, kn);
    barrier_lds();  // prev ds_reads done; prefetch stays in flight
    *(uint4*)&As[sr][sc8] = a0c;
    *(uint4*)&As[sr + 32][sc8] = a1c;
    *(uint4*)&Bs[sr][sc8] = b0c;
    *(uint4*)&Bs[sr + 32][sc8] = b1c;
    barrier_lds();
#pragma unroll
    for (int kk = 0; kk < 64; kk += 32) {
      bf16x8 a0 = *(const bf16x8*)&As[wm + lm][kk + quad * 8];
      bf16x8 a1 = *(const bf16x8*)&As[wm + 16 + lm][kk + quad * 8];
      bf16x8 b0 = *(const bf16x8*)&Bs[wn + lm][kk + quad * 8];
      bf16x8 b1 = *(const bf16x8*)&Bs[wn + 16 + lm][kk + quad * 8];
      acc[0][0] = __builtin_amdgcn_mfma_f32_16x16x32_bf16(a0, b0, acc[0][0], 0, 0, 0);
      acc[0][1] = __builtin_amdgcn_mfma_f32_16x16x32_bf16(a0, b1, acc[0][1], 0, 0, 0);
      acc[1][0] = __builtin_amdgcn_mfma_f32_16x16x32_bf16(a1, b0, acc[1][0], 0, 0, 0);
      acc[1][1] = __builtin_amdgcn_mfma_f32_16x16x32_bf16(a1, b1, acc[1][1], 0, 0, 0);
    }
    a0c = a0n; a1c = a1n; b0c = b0n; b1c = b1n;
  }
#pragma unroll
  for (int mt = 0; mt < 2; ++mt)
#pragma unroll
    for (int nt = 0; nt < 2; ++nt) {
      int col = n0 + wn + nt * 16 + lm;
      float bv = (flags & 1) ? bias[col] : 0.f;
#pragma unroll
      for (int t = 0; t < 4; ++t) {
        int row = m0 + wm + mt * 16 + quad * 4 + t;
        if (row < M) {
          float v = acc[mt][nt][t] + bv;
          if (flags & 2) v = fmaxf(v, 0.f);
          if (flags & 4) Cb[(size_t)row * N + col] = f2bf(v);
          else C[(size_t)row * N + col] = v;
        }
      }
    }
}

// ------- MFMA flash attention, reg-prefetch + lgkm-only barriers ----------
__global__ __launch_bounds__(256) void k_attn(const ushort_t* __restrict__ qkv,
                                              const ushort_t* __restrict__ r,
                                              const float* __restrict__ rwb,
                                              const float* __restrict__ rrb,
                                              ushort_t* __restrict__ attn) {
  const int h = blockIdx.y;
  const int qt = 64 - blockIdx.x;  // heavy q-tiles dispatch first
  const int i0 = qt * 32;
  const int tid = threadIdx.x;
  const int lane = tid & 63, wv = tid >> 6;
  const int lm = lane & 15, quad = lane >> 4;

  __shared__ short qw[32][72];     // (q+rwb) bf16 [i][d]
  __shared__ short qr[33][72];     // (q+rrb) bf16 [i][d]
  __shared__ short ks_[32][72];    // K tile [j][d]
  __shared__ short vsT[64][70];    // V^T [d][j]
  __shared__ short rband[64][72];  // circular r band, slot = kidx & 63
  __shared__ short pb[32][40];     // P bf16 [i][j]
  __shared__ float rm[14][68];     // r rows 0..13 fp32 (mem-block wrap)
  __shared__ float st[32][33];     // AC fp32 [i][j]
  __shared__ float bdf[32][66];    // BDfull fp32 [i][t]
  __shared__ float m_s[32], l_s[32], alpha_s[32];

  const uint4 zero4 = make_uint4(0, 0, 0, 0);
  const int krr = tid >> 3, kc8 = (tid & 7) * 8;  // K/rband staging coords
  const int vrr = tid >> 4, vc4 = tid & 15;       // V staging coords
  const int kb0 = TT - 32 - i0;

  auto loadK = [&](int j0) -> uint4 {
    return *(const uint4*)&qkv[(size_t)(j0 + krr) * QKV_N + DM + h * DH + kc8];
  };
  auto loadBand = [&](int kidx) -> uint4 {
    return (kidx < TT) ? *(const uint4*)&r[(size_t)kidx * DM + h * DH + kc8]
                       : zero4;
  };

  {  // stage qw/qr with bias add
    int rr = tid >> 3, c8 = (tid & 7) * 8;
    uint4 qv = *(const uint4*)&qkv[(size_t)(i0 + rr) * QKV_N + h * DH + c8];
    float f[8]; unpack8(qv, f);
    float4 w0 = *(const float4*)&rwb[h * DH + c8];
    float4 w1 = *(const float4*)&rwb[h * DH + c8 + 4];
    float4 r0 = *(const float4*)&rrb[h * DH + c8];
    float4 r1 = *(const float4*)&rrb[h * DH + c8 + 4];
    uint4 ow, orr;
    ow.x = pack2(f2bf(f[0] + w0.x), f2bf(f[1] + w0.y));
    ow.y = pack2(f2bf(f[2] + w0.z), f2bf(f[3] + w0.w));
    ow.z = pack2(f2bf(f[4] + w1.x), f2bf(f[5] + w1.y));
    ow.w = pack2(f2bf(f[6] + w1.z), f2bf(f[7] + w1.w));
    orr.x = pack2(f2bf(f[0] + r0.x), f2bf(f[1] + r0.y));
    orr.y = pack2(f2bf(f[2] + r0.z), f2bf(f[3] + r0.w));
    orr.z = pack2(f2bf(f[4] + r1.x), f2bf(f[5] + r1.y));
    orr.w = pack2(f2bf(f[6] + r1.z), f2bf(f[7] + r1.w));
    *(uint4*)&qw[rr][c8] = ow;
    *(uint4*)&qr[rr][c8] = orr;
  }
  if (tid < 112) {  // rm staging (fp32)
    int rr = tid >> 3, c8 = (tid & 7) * 8;
    uint4 v = *(const uint4*)&r[(size_t)rr * DM + h * DH + c8];
    float f[8]; unpack8(v, f);
#pragma unroll
    for (int j = 0; j < 8; ++j) rm[rr][c8 + j] = f[j];
  }
  if (tid < 32) { m_s[tid] = -INFINITY; l_s[tid] = 0.f; }

  f32x4 oA = (f32x4)(0.f);  // O^T accum, d-tile=wv, i = i0+lm
  f32x4 oB = (f32x4)(0.f);  // i = i0+16+lm

  // ---- pipeline prologue: tile 0 into registers ----
  uint4 kcur = loadK(0);
  const ushort_t* vp0 = &qkv[(size_t)(2 * vrr) * QKV_N + 2 * DM + h * DH + vc4 * 4];
  uint2 v0cur = *(const uint2*)vp0, v1cur = *(const uint2*)(vp0 + QKV_N);
  uint4 band0 = loadBand(kb0 + krr);
  uint4 band1 = loadBand(kb0 + 32 + krr);
  uint4 bcur = zero4;

  for (int jt = 0; jt <= qt; ++jt) {
    const int j0 = jt * 32;
    const int kb = kb0 + 32 * jt;
    // ---- issue next tile's loads (clamped reload on last iteration) ----
    const int jn = (jt < qt) ? j0 + 32 : j0;
    uint4 knext = loadK(jn);
    const ushort_t* vpn = &qkv[(size_t)(jn + 2 * vrr) * QKV_N + 2 * DM + h * DH + vc4 * 4];
    uint2 v0n = *(const uint2*)vpn, v1n = *(const uint2*)(vpn + QKV_N);
    uint4 bnext = loadBand((jt < qt) ? (kb + 64 + krr) : (kb0 + krr));

    barrier_lds();  // prior iteration's ds ops done; vmcnt stays in flight
    // ---- write current tile (loaded last iteration) to LDS ----
    *(uint4*)&ks_[krr][kc8] = kcur;
    {
      ushort_t a0 = (ushort_t)(v0cur.x & 0xffffu), a1 = (ushort_t)(v0cur.x >> 16);
      ushort_t a2 = (ushort_t)(v0cur.y & 0xffffu), a3 = (ushort_t)(v0cur.y >> 16);
      ushort_t c0 = (ushort_t)(v1cur.x & 0xffffu), c1 = (ushort_t)(v1cur.x >> 16);
      ushort_t c2 = (ushort_t)(v1cur.y & 0xffffu), c3 = (ushort_t)(v1cur.y >> 16);
      *(unsigned int*)&vsT[vc4 * 4 + 0][2 * vrr] = pack2(a0, c0);
      *(unsigned int*)&vsT[vc4 * 4 + 1][2 * vrr] = pack2(a1, c1);
      *(unsigned int*)&vsT[vc4 * 4 + 2][2 * vrr] = pack2(a2, c2);
      *(unsigned int*)&vsT[vc4 * 4 + 3][2 * vrr] = pack2(a3, c3);
    }
    if (jt == 0) {
      *(uint4*)&rband[(kb0 + krr) & 63][kc8] = band0;
      *(uint4*)&rband[(kb0 + 32 + krr) & 63][kc8] = band1;
    } else {
      *(uint4*)&rband[(kb + 32 + krr) & 63][kc8] = bcur;
    }
    barrier_lds();

    {  // ---- phase B: AC + BDfull MFMAs -> LDS ----
      const int acit = wv >> 1, acjt = wv & 1;
      f32x4 ac = (f32x4)(0.f);
#pragma unroll
      for (int k2 = 0; k2 < 64; k2 += 32) {
        bf16x8 a = *(const bf16x8*)&qw[acit * 16 + lm][k2 + quad * 8];
        bf16x8 b = *(const bf16x8*)&ks_[acjt * 16 + lm][k2 + quad * 8];
        ac = __builtin_amdgcn_mfma_f32_16x16x32_bf16(a, b, ac, 0, 0, 0);
      }
#pragma unroll
      for (int t = 0; t < 4; ++t)
        st[acit * 16 + quad * 4 + t][acjt * 16 + lm] = ac[t];

      const int brt = wv >> 1, bc0 = wv & 1, bc1 = (wv & 1) + 2;
      const int pr0 = (kb + bc0 * 16 + lm) & 63;  // physical circular rows
      const int pr1 = (kb + bc1 * 16 + lm) & 63;
      f32x4 bd0 = (f32x4)(0.f), bd1 = (f32x4)(0.f);
#pragma unroll
      for (int k2 = 0; k2 < 64; k2 += 32) {
        bf16x8 a = *(const bf16x8*)&qr[brt * 16 + lm][k2 + quad * 8];
        bf16x8 b0 = *(const bf16x8*)&rband[pr0][k2 + quad * 8];
        bf16x8 b1 = *(const bf16x8*)&rband[pr1][k2 + quad * 8];
        bd0 = __builtin_amdgcn_mfma_f32_16x16x32_bf16(a, b0, bd0, 0, 0, 0);
        bd1 = __builtin_amdgcn_mfma_f32_16x16x32_bf16(a, b1, bd1, 0, 0, 0);
      }
#pragma unroll
      for (int t = 0; t < 4; ++t) {
        bdf[brt * 16 + quad * 4 + t][bc0 * 16 + lm] = bd0[t];
        bdf[brt * 16 + quad * 4 + t][bc1 * 16 + lm] = bd1[t];
      }
    }
    barrier_lds();

    {  // ---- phase C: score assembly + online softmax ----
      const int ii = tid >> 3, g = tid & 7, jjb = g * 4;
      const int i = i0 + ii;
      float sreg[4];
#pragma unroll
      for (int u = 0; u < 4; ++u) {
        int j = j0 + jjb + u;
        float acv = st[ii][jjb + u];
        float s;
        if (j <= i) {
          s = (acv + bdf[ii][jjb + u - ii + 31]) * ATT_SCALE;
        } else {
          bool inmem = (i < NMTOK && j < NMTOK) ||
                       (i >= TT - NMTOK && j >= TT - NMTOK);
          if (!inmem) s = -1e30f;
          else if (j == i + 1) s = acv * ATT_SCALE;  // rel_shift zero-pad entry
          else {
            float b2 = 0.f;
            const int rrow = j - i - 2;
            for (int d = 0; d < 64; ++d)
              b2 += bfbits2f(((unsigned int)(ushort_t)qr[ii + 1][d]) << 16) *
                    rm[rrow][d];
            s = (acv + b2) * ATT_SCALE;
          }
        }
        sreg[u] = s;
      }
      float tmax = fmaxf(fmaxf(sreg[0], sreg[1]), fmaxf(sreg[2], sreg[3]));
#pragma unroll
      for (int off = 1; off < 8; off <<= 1) tmax = fmaxf(tmax, __shfl_xor(tmax, off));
      const float mold = m_s[ii];
      const float mnew = fmaxf(mold, tmax);
      const float alpha = __expf(mold - mnew);
      float p[4], psum = 0.f;
#pragma unroll
      for (int u = 0; u < 4; ++u) { p[u] = __expf(sreg[u] - mnew); psum += p[u]; }
#pragma unroll
      for (int off = 1; off < 8; off <<= 1) psum += __shfl_xor(psum, off);
      uint2 pk;
      pk.x = pack2(f2bf(p[0]), f2bf(p[1]));
      pk.y = pack2(f2bf(p[2]), f2bf(p[3]));
      *(uint2*)&pb[ii][jjb] = pk;
      if (g == 0) {
        m_s[ii] = mnew;
        l_s[ii] = l_s[ii] * alpha + psum;
        alpha_s[ii] = alpha;
      }
    }
    barrier_lds();

    {  // ---- phase D: O^T = O^T*alpha + V^T P^T ----
      float a0 = alpha_s[lm], a1 = alpha_s[16 + lm];
      union { bf16x8 v; unsigned int u[4]; } av;
      const unsigned int* vp = (const unsigned int*)&vsT[wv * 16 + lm][quad * 8];
      av.u[0] = vp[0]; av.u[1] = vp[1]; av.u[2] = vp[2]; av.u[3] = vp[3];
      bf16x8 p0 = *(const bf16x8*)&pb[lm][quad * 8];
      bf16x8 p1 = *(const bf16x8*)&pb[16 + lm][quad * 8];
#pragma unroll
      for (int t = 0; t < 4; ++t) { oA[t] *= a0; oB[t] *= a1; }
      oA = __builtin_amdgcn_mfma_f32_16x16x32_bf16(av.v, p0, oA, 0, 0, 0);
      oB = __builtin_amdgcn_mfma_f32_16x16x32_bf16(av.v, p1, oB, 0, 0, 0);
    }
    kcur = knext; v0cur = v0n; v1cur = v1n; bcur = bnext;
  }

  {  // final: scale by 1/l and store O (lane = i-col, quad*4 = d rows)
    float l0 = 1.f / l_s[lm], l1 = 1.f / l_s[16 + lm];
    ushort_t o0[4], o1[4];
#pragma unroll
    for (int t = 0; t < 4; ++t) {
      o0[t] = f2bf(oA[t] * l0);
      o1[t] = f2bf(oB[t] * l1);
    }
    size_t b0 = (size_t)(i0 + lm) * DM + h * DH + wv * 16 + quad * 4;
    size_t b1 = (size_t)(i0 + 16 + lm) * DM + h * DH + wv * 16 + quad * 4;
    *(uint2*)&attn[b0] = *(uint2*)o0;
    *(uint2*)&attn[b1] = *(uint2*)o1;
  }
}

// ---------------- w = LayerNorm(w + delta) * g + b; writes fp32 + bf16 ----
__global__ __launch_bounds__(256) void k_addln(float* __restrict__ w,
                                               ushort_t* __restrict__ wb,
                                               const float* __restrict__ delta,
                                               const float* __restrict__ gamma,
                                               const float* __restrict__ beta) {
  const int row = blockIdx.x;
  const int tid = threadIdx.x;
  __shared__ float red[4], red2[4];
  size_t base = (size_t)row * DM;
  float x0 = w[base + tid] + delta[base + tid];
  float x1 = w[base + tid + 256] + delta[base + tid + 256];
  float s = x0 + x1;
#pragma unroll
  for (int off = 1; off < 64; off <<= 1) s += __shfl_xor(s, off);
  if ((tid & 63) == 0) red[tid >> 6] = s;
  __syncthreads();
  float mu = (red[0] + red[1] + red[2] + red[3]) * (1.f / 512.f);
  float d0 = x0 - mu, d1 = x1 - mu;
  float v = d0 * d0 + d1 * d1;
#pragma unroll
  for (int off = 1; off < 64; off <<= 1) v += __shfl_xor(v, off);
  if ((tid & 63) == 0) red2[tid >> 6] = v;
  __syncthreads();
  float var = (red2[0] + red2[1] + red2[2] + red2[3]) * (1.f / 512.f);
  float rstd = rsqrtf(var + 1e-5f);
  float o0 = d0 * rstd * gamma[tid] + beta[tid];
  float o1 = d1 * rstd * gamma[tid + 256] + beta[tid + 256];
  w[base + tid] = o0;
  w[base + tid + 256] = o1;
  wb[base + tid] = f2bf(o0);
  wb[base + tid + 256] = f2bf(o1);
}

__global__ __launch_bounds__(256) void k_copy(const float* __restrict__ src,
                                              float* __restrict__ dst) {
  int idx = blockIdx.x * 256 + threadIdx.x;
  if (idx < TT * DM) dst[idx] = src[idx];
}

extern "C" void kernel_launch(void* const* d_in, const int* in_sizes, int n_in,
                              void* d_out, int out_size, void* d_ws, size_t ws_size,
                              hipStream_t stream) {
  const float* we   = (const float*)d_in[0];
  const float* mem  = (const float*)d_in[1];
  const float* Wqkv = (const float*)d_in[2];
  const float* Wr   = (const float*)d_in[3];
  const float* Wo   = (const float*)d_in[4];
  const float* ln1s = (const float*)d_in[5];
  const float* ln1b = (const float*)d_in[6];
  const float* W1   = (const float*)d_in[7];
  const float* b1   = (const float*)d_in[8];
  const float* W2   = (const float*)d_in[9];
  const float* b2   = (const float*)d_in[10];
  const float* ln2s = (const float*)d_in[11];
  const float* ln2b = (const float*)d_in[12];
  const float* rwb  = (const float*)d_in[13];
  const float* rrb  = (const float*)d_in[14];

  // ---- workspace layout (~30 MB) ----
  float* w     = (float*)d_ws;                        // TT*DM fp32
  float* proj  = w + (size_t)TT * DM;                 // TT*DM fp32 (ff2 overlays)
  ushort_t* wb    = (ushort_t*)(proj + (size_t)TT * DM);  // TT*DM bf16
  ushort_t* posb  = wb + (size_t)TT * DM;             // TT*DM bf16
  ushort_t* attnb = posb + (size_t)TT * DM;           // TT*DM bf16
  ushort_t* qkvb  = attnb + (size_t)TT * DM;          // TT*1536 bf16
  ushort_t* rbg   = qkvb + (size_t)TT * QKV_N;        // TT*DM bf16
  ushort_t* WtAll = rbg + (size_t)TT * DM;            // 3407872 shorts: layer's 5 mats
  ushort_t* ff1b  = qkvb;                             // TT*DI bf16 overlay
  float* ff2   = proj;
  const size_t OFF_QKVT = 0, OFF_WRT = 786432, OFF_WOT = 1048576,
               OFF_W1T = 1310720, OFF_W2T = 2359296;

  k_build<<<(TT * DM + 255) / 256, 256, 0, stream>>>(we, mem, w, wb, posb);

  dim3 gQKV(QKV_N / 64, 33), gDMg(DM / 64, 33), gDIg(DI / 64, 33);
  dim3 gA(65, NH);

  for (int l = 0; l < NLAYER; ++l) {
    k_transpose_all<<<3328, 256, 0, stream>>>(Wqkv, Wr, Wo, W1, W2, WtAll, l);
    k_gemm_mfma<<<gQKV, 256, 0, stream>>>(wb, WtAll + OFF_QKVT, nullptr, nullptr, qkvb,
                                          TT, QKV_N, DM, 4);
    k_gemm_mfma<<<gDMg, 256, 0, stream>>>(posb, WtAll + OFF_WRT, nullptr, nullptr, rbg,
                                          TT, DM, DM, 4);
    k_attn<<<gA, 256, 0, stream>>>(qkvb, rbg, rwb, rrb, attnb);
    k_gemm_mfma<<<gDMg, 256, 0, stream>>>(attnb, WtAll + OFF_WOT, nullptr, proj, nullptr,
                                          TT, DM, DM, 0);
    k_addln<<<TT, 256, 0, stream>>>(w, wb, proj, ln1s + (size_t)l * DM, ln1b + (size_t)l * DM);
    k_gemm_mfma<<<gDIg, 256, 0, stream>>>(wb, WtAll + OFF_W1T, b1 + (size_t)l * DI, nullptr, ff1b,
                                          TT, DI, DM, 1 | 2 | 4);
    k_gemm_mfma<<<gDMg, 256, 0, stream>>>(ff1b, WtAll + OFF_W2T, b2 + (size_t)l * DM, ff2, nullptr,
                                          TT, DM, DI, 1);
    k_addln<<<TT, 256, 0, stream>>>(w, wb, ff2, ln2s + (size_t)l * DM, ln2b + (size_t)l * DM);
  }
  k_copy<<<(TT * DM + 255) / 256, 256, 0, stream>>>(w, (float*)d_out);
}

// Round 7
// 935.366 us; speedup vs baseline: 1.1141x; 1.1141x over previous
//
#include <hip/hip_runtime.h>
#include <hip/hip_bf16.h>
#include <math.h>

#define TT 2080
#define DM 512
#define DI 2048
#define NH 8
#define DH 64
#define NMTOK 16
#define NLAYER 4
#define QKV_N 1536
#define ATT_SCALE 0.125f
#define SPLIT 4

typedef short bf16x8 __attribute__((ext_vector_type(8)));
typedef float f32x4 __attribute__((ext_vector_type(4)));
typedef unsigned short ushort_t;

__device__ __forceinline__ ushort_t f2bf(float f) {
  __hip_bfloat16 h = __float2bfloat16(f);
  return *reinterpret_cast<ushort_t*>(&h);
}
__device__ __forceinline__ float bfbits2f(unsigned int hi_bits) {
  return __uint_as_float(hi_bits);
}
__device__ __forceinline__ void unpack8(uint4 v, float* f) {
  f[0] = bfbits2f(v.x << 16); f[1] = bfbits2f(v.x & 0xffff0000u);
  f[2] = bfbits2f(v.y << 16); f[3] = bfbits2f(v.y & 0xffff0000u);
  f[4] = bfbits2f(v.z << 16); f[5] = bfbits2f(v.z & 0xffff0000u);
  f[6] = bfbits2f(v.w << 16); f[7] = bfbits2f(v.w & 0xffff0000u);
}
__device__ __forceinline__ unsigned int pack2(ushort_t lo, ushort_t hi) {
  return (unsigned int)lo | ((unsigned int)hi << 16);
}
// Barrier draining LDS ops only — leaves global (vmcnt) loads in flight.
__device__ __forceinline__ void barrier_lds() {
  asm volatile("s_waitcnt lgkmcnt(0)" ::: "memory");
  __builtin_amdgcn_s_barrier();
}

// ---------------- build w (fp32+bf16) and pos_emb (bf16) ------------------
__global__ __launch_bounds__(256) void k_build(const float* __restrict__ we,
                                               const float* __restrict__ mem,
                                               float* __restrict__ w,
                                               ushort_t* __restrict__ wb,
                                               ushort_t* __restrict__ posb) {
  int idx = blockIdx.x * 256 + threadIdx.x;
  if (idx >= TT * DM) return;
  int t = idx >> 9, d = idx & 511;
  float v;
  if (t < NMTOK) v = mem[t * DM + d];
  else if (t < NMTOK + 2048) v = we[(t - NMTOK) * DM + d];
  else v = mem[(t - (NMTOK + 2048)) * DM + d];
  w[idx] = v;
  wb[idx] = f2bf(v);
  float p = (float)(TT - 1 - t);
  int i2 = d & 255;
  float freq = 1.0f / powf(10000.f, ((float)(2 * i2)) / 512.f);
  float ang = p * freq;
  posb[idx] = f2bf((d < 256) ? sinf(ang) : cosf(ang));
}

// ---- batched transpose+cast of all 5 weight mats of one layer ------------
__global__ __launch_bounds__(256) void k_transpose_all(
    const float* __restrict__ Wqkv, const float* __restrict__ Wr,
    const float* __restrict__ Wo, const float* __restrict__ W1,
    const float* __restrict__ W2, ushort_t* __restrict__ dstAll, int l) {
  __shared__ float t[32][33];
  const int tid = threadIdx.x;
  int idx = blockIdx.x;
  const float* src;
  ushort_t* dst;
  int K, N, local;
  if (idx < 768)       { src = Wqkv + (size_t)l * 512 * 1536; dst = dstAll;          K = 512;  N = 1536; local = idx; }
  else if (idx < 1024) { src = Wr   + (size_t)l * 512 * 512;  dst = dstAll + 786432; K = 512;  N = 512;  local = idx - 768; }
  else if (idx < 1280) { src = Wo   + (size_t)l * 512 * 512;  dst = dstAll + 1048576; K = 512; N = 512;  local = idx - 1024; }
  else if (idx < 2304) { src = W1   + (size_t)l * 512 * 2048; dst = dstAll + 1310720; K = 512; N = 2048; local = idx - 1280; }
  else                 { src = W2   + (size_t)l * 2048 * 512; dst = dstAll + 2359296; K = 2048; N = 512; local = idx - 2304; }
  const int ntiles = N / 32;
  const int n0 = (local % ntiles) * 32, k0 = (local / ntiles) * 32;
#pragma unroll
  for (int p = 0; p < 4; ++p) {
    int row = (tid >> 5) + 8 * p, col = tid & 31;
    t[row][col] = src[(size_t)(k0 + row) * N + n0 + col];
  }
  __syncthreads();
#pragma unroll
  for (int p = 0; p < 4; ++p) {
    int n = (tid >> 5) + 8 * p, k = tid & 31;
    dst[(size_t)(n0 + n) * K + k0 + k] = f2bf(t[k][n]);
  }
}

// -------- bf16 MFMA GEMM 64x64, register-prefetch + lgkm-only barriers ----
// flags: 1=+bias, 2=relu, 4=bf16 output (else fp32)
__global__ __launch_bounds__(256) void k_gemm_mfma(const ushort_t* __restrict__ A,
                                                   const ushort_t* __restrict__ Bt,
                                                   const float* __restrict__ bias,
                                                   float* __restrict__ C,
                                                   ushort_t* __restrict__ Cb,
                                                   int M, int N, int K, int flags) {
  __shared__ short As[64][72];
  __shared__ short Bs[64][72];
  const int tid = threadIdx.x;
  const int m0 = blockIdx.y * 64, n0 = blockIdx.x * 64;
  const int lane = tid & 63, wv = tid >> 6;
  const int wm = (wv >> 1) * 32, wn = (wv & 1) * 32;
  const int lm = lane & 15, quad = lane >> 4;
  const int sr = tid >> 3, sc8 = (tid & 7) * 8;  // staging row / col chunk

  const uint4 zero4 = make_uint4(0, 0, 0, 0);
  f32x4 acc[2][2];
#pragma unroll
  for (int a = 0; a < 2; ++a)
#pragma unroll
    for (int b = 0; b < 2; ++b) acc[a][b] = (f32x4)(0.f);

  auto loadA = [&](int row, int k0) -> uint4 {
    return (m0 + row < M) ? *(const uint4*)&A[(size_t)(m0 + row) * K + k0 + sc8]
                          : zero4;
  };
  auto loadB = [&](int row, int k0) -> uint4 {
    return *(const uint4*)&Bt[(size_t)(n0 + row) * K + k0 + sc8];
  };

  uint4 a0c = loadA(sr, 0), a1c = loadA(sr + 32, 0);
  uint4 b0c = loadB(sr, 0), b1c = loadB(sr + 32, 0);

  for (int k0 = 0; k0 < K; k0 += 64) {
    const int kn = (k0 + 64 < K) ? k0 + 64 : k0;  // clamped reload on last iter
    uint4 a0n = loadA(sr, kn), a1n = loadA(sr + 32, kn);
    uint4 b0n = loadB(sr, kn), b1n = loadB(sr + 32, kn);
    barrier_lds();  // prev ds_reads done; prefetch stays in flight
    *(uint4*)&As[sr][sc8] = a0c;
    *(uint4*)&As[sr + 32][sc8] = a1c;
    *(uint4*)&Bs[sr][sc8] = b0c;
    *(uint4*)&Bs[sr + 32][sc8] = b1c;
    barrier_lds();
#pragma unroll
    for (int kk = 0; kk < 64; kk += 32) {
      bf16x8 a0 = *(const bf16x8*)&As[wm + lm][kk + quad * 8];
      bf16x8 a1 = *(const bf16x8*)&As[wm + 16 + lm][kk + quad * 8];
      bf16x8 b0 = *(const bf16x8*)&Bs[wn + lm][kk + quad * 8];
      bf16x8 b1 = *(const bf16x8*)&Bs[wn + 16 + lm][kk + quad * 8];
      acc[0][0] = __builtin_amdgcn_mfma_f32_16x16x32_bf16(a0, b0, acc[0][0], 0, 0, 0);
      acc[0][1] = __builtin_amdgcn_mfma_f32_16x16x32_bf16(a0, b1, acc[0][1], 0, 0, 0);
      acc[1][0] = __builtin_amdgcn_mfma_f32_16x16x32_bf16(a1, b0, acc[1][0], 0, 0, 0);
      acc[1][1] = __builtin_amdgcn_mfma_f32_16x16x32_bf16(a1, b1, acc[1][1], 0, 0, 0);
    }
    a0c = a0n; a1c = a1n; b0c = b0n; b1c = b1n;
  }
#pragma unroll
  for (int mt = 0; mt < 2; ++mt)
#pragma unroll
    for (int nt = 0; nt < 2; ++nt) {
      int col = n0 + wn + nt * 16 + lm;
      float bv = (flags & 1) ? bias[col] : 0.f;
#pragma unroll
      for (int t = 0; t < 4; ++t) {
        int row = m0 + wm + mt * 16 + quad * 4 + t;
        if (row < M) {
          float v = acc[mt][nt][t] + bv;
          if (flags & 2) v = fmaxf(v, 0.f);
          if (flags & 4) Cb[(size_t)row * N + col] = f2bf(v);
          else C[(size_t)row * N + col] = v;
        }
      }
    }
}

// ------- MFMA flash attention, split-j partials (flash split-K style) -----
// Chunk c handles jt = c, c+SPLIT, ... <= qt. Emits partial O (un-normalized,
// bf16, O[i][d] layout), m, l. Combine kernel merges the <=4 chunks.
__global__ __launch_bounds__(256) void k_attn(const ushort_t* __restrict__ qkv,
                                              const ushort_t* __restrict__ r,
                                              const float* __restrict__ rwb,
                                              const float* __restrict__ rrb,
                                              float* __restrict__ mlP,
                                              ushort_t* __restrict__ opP) {
  const int h = blockIdx.y;
  const int qt = 64 - blockIdx.x;  // heavy q-tiles dispatch first
  const int c = blockIdx.z;
  if (c > qt) return;  // empty chunk
  const int i0 = qt * 32;
  const int tid = threadIdx.x;
  const int lane = tid & 63, wv = tid >> 6;
  const int lm = lane & 15, quad = lane >> 4;

  __shared__ short qw[32][72];     // (q+rwb) bf16 [i][d]
  __shared__ short qr[33][72];     // (q+rrb) bf16 [i][d]
  __shared__ short ks_[32][72];    // K tile [j][d]
  __shared__ short vsT[64][70];    // V^T [d][j]
  __shared__ short rband[64][72];  // r band [t][d], kidx = kb + t
  __shared__ short pb[32][40];     // P bf16 [i][j]
  __shared__ float rm[14][68];     // r rows 0..13 fp32 (mem-block wrap)
  __shared__ float st[32][33];     // AC fp32 [i][j]
  __shared__ float bdf[32][66];    // BDfull fp32 [i][t]
  __shared__ float m_s[32], l_s[32], alpha_s[32];

  const uint4 zero4 = make_uint4(0, 0, 0, 0);
  const int krr = tid >> 3, kc8 = (tid & 7) * 8;  // K/rband staging coords
  const int vrr = tid >> 4, vc4 = tid & 15;       // V staging coords
  const int kb0 = TT - 32 - i0;

  auto loadK = [&](int j0) -> uint4 {
    return *(const uint4*)&qkv[(size_t)(j0 + krr) * QKV_N + DM + h * DH + kc8];
  };
  auto loadBand = [&](int kidx) -> uint4 {
    return (kidx < TT) ? *(const uint4*)&r[(size_t)kidx * DM + h * DH + kc8]
                       : zero4;
  };

  {  // stage qw/qr with bias add
    int rr = tid >> 3, c8 = (tid & 7) * 8;
    uint4 qv = *(const uint4*)&qkv[(size_t)(i0 + rr) * QKV_N + h * DH + c8];
    float f[8]; unpack8(qv, f);
    float4 w0 = *(const float4*)&rwb[h * DH + c8];
    float4 w1 = *(const float4*)&rwb[h * DH + c8 + 4];
    float4 r0 = *(const float4*)&rrb[h * DH + c8];
    float4 r1 = *(const float4*)&rrb[h * DH + c8 + 4];
    uint4 ow, orr;
    ow.x = pack2(f2bf(f[0] + w0.x), f2bf(f[1] + w0.y));
    ow.y = pack2(f2bf(f[2] + w0.z), f2bf(f[3] + w0.w));
    ow.z = pack2(f2bf(f[4] + w1.x), f2bf(f[5] + w1.y));
    ow.w = pack2(f2bf(f[6] + w1.z), f2bf(f[7] + w1.w));
    orr.x = pack2(f2bf(f[0] + r0.x), f2bf(f[1] + r0.y));
    orr.y = pack2(f2bf(f[2] + r0.z), f2bf(f[3] + r0.w));
    orr.z = pack2(f2bf(f[4] + r1.x), f2bf(f[5] + r1.y));
    orr.w = pack2(f2bf(f[6] + r1.z), f2bf(f[7] + r1.w));
    *(uint4*)&qw[rr][c8] = ow;
    *(uint4*)&qr[rr][c8] = orr;
  }
  if (tid < 112) {  // rm staging (fp32)
    int rr = tid >> 3, c8 = (tid & 7) * 8;
    uint4 v = *(const uint4*)&r[(size_t)rr * DM + h * DH + c8];
    float f[8]; unpack8(v, f);
#pragma unroll
    for (int j = 0; j < 8; ++j) rm[rr][c8 + j] = f[j];
  }
  if (tid < 32) { m_s[tid] = -INFINITY; l_s[tid] = 0.f; }

  f32x4 oA = (f32x4)(0.f);  // O^T accum, d-tile=wv, i = i0+lm
  f32x4 oB = (f32x4)(0.f);  // i = i0+16+lm

  // ---- pipeline prologue: first chunk tile into registers ----
  uint4 kcur = loadK(c * 32);
  const ushort_t* vp0 = &qkv[(size_t)(c * 32 + 2 * vrr) * QKV_N + 2 * DM + h * DH + vc4 * 4];
  uint2 v0cur = *(const uint2*)vp0, v1cur = *(const uint2*)(vp0 + QKV_N);
  uint4 band0cur = loadBand(kb0 + 32 * c + krr);
  uint4 band1cur = loadBand(kb0 + 32 * c + 32 + krr);

  for (int jt = c; jt <= qt; jt += SPLIT) {
    const int j0 = jt * 32;
    // ---- issue next tile's loads (clamped reload on last iteration) ----
    const int jn = (jt + SPLIT <= qt) ? jt + SPLIT : jt;
    uint4 knext = loadK(jn * 32);
    const ushort_t* vpn = &qkv[(size_t)(jn * 32 + 2 * vrr) * QKV_N + 2 * DM + h * DH + vc4 * 4];
    uint2 v0n = *(const uint2*)vpn, v1n = *(const uint2*)(vpn + QKV_N);
    uint4 b0n = loadBand(kb0 + 32 * jn + krr);
    uint4 b1n = loadBand(kb0 + 32 * jn + 32 + krr);

    barrier_lds();  // prior iteration's ds ops done; vmcnt stays in flight
    // ---- write current tile (loaded last iteration) to LDS ----
    *(uint4*)&ks_[krr][kc8] = kcur;
    {
      ushort_t a0 = (ushort_t)(v0cur.x & 0xffffu), a1 = (ushort_t)(v0cur.x >> 16);
      ushort_t a2 = (ushort_t)(v0cur.y & 0xffffu), a3 = (ushort_t)(v0cur.y >> 16);
      ushort_t c0 = (ushort_t)(v1cur.x & 0xffffu), c1 = (ushort_t)(v1cur.x >> 16);
      ushort_t c2 = (ushort_t)(v1cur.y & 0xffffu), c3 = (ushort_t)(v1cur.y >> 16);
      *(unsigned int*)&vsT[vc4 * 4 + 0][2 * vrr] = pack2(a0, c0);
      *(unsigned int*)&vsT[vc4 * 4 + 1][2 * vrr] = pack2(a1, c1);
      *(unsigned int*)&vsT[vc4 * 4 + 2][2 * vrr] = pack2(a2, c2);
      *(unsigned int*)&vsT[vc4 * 4 + 3][2 * vrr] = pack2(a3, c3);
    }
    *(uint4*)&rband[krr][kc8] = band0cur;
    *(uint4*)&rband[krr + 32][kc8] = band1cur;
    barrier_lds();

    {  // ---- phase B: AC + BDfull MFMAs -> LDS ----
      const int acit = wv >> 1, acjt = wv & 1;
      f32x4 ac = (f32x4)(0.f);
#pragma unroll
      for (int k2 = 0; k2 < 64; k2 += 32) {
        bf16x8 a = *(const bf16x8*)&qw[acit * 16 + lm][k2 + quad * 8];
        bf16x8 b = *(const bf16x8*)&ks_[acjt * 16 + lm][k2 + quad * 8];
        ac = __builtin_amdgcn_mfma_f32_16x16x32_bf16(a, b, ac, 0, 0, 0);
      }
#pragma unroll
      for (int t = 0; t < 4; ++t)
        st[acit * 16 + quad * 4 + t][acjt * 16 + lm] = ac[t];

      const int brt = wv >> 1, bc0 = wv & 1, bc1 = (wv & 1) + 2;
      f32x4 bd0 = (f32x4)(0.f), bd1 = (f32x4)(0.f);
#pragma unroll
      for (int k2 = 0; k2 < 64; k2 += 32) {
        bf16x8 a = *(const bf16x8*)&qr[brt * 16 + lm][k2 + quad * 8];
        bf16x8 b0 = *(const bf16x8*)&rband[bc0 * 16 + lm][k2 + quad * 8];
        bf16x8 b1 = *(const bf16x8*)&rband[bc1 * 16 + lm][k2 + quad * 8];
        bd0 = __builtin_amdgcn_mfma_f32_16x16x32_bf16(a, b0, bd0, 0, 0, 0);
        bd1 = __builtin_amdgcn_mfma_f32_16x16x32_bf16(a, b1, bd1, 0, 0, 0);
      }
#pragma unroll
      for (int t = 0; t < 4; ++t) {
        bdf[brt * 16 + quad * 4 + t][bc0 * 16 + lm] = bd0[t];
        bdf[brt * 16 + quad * 4 + t][bc1 * 16 + lm] = bd1[t];
      }
    }
    barrier_lds();

    {  // ---- phase C: score assembly + online softmax ----
      const int ii = tid >> 3, g = tid & 7, jjb = g * 4;
      const int i = i0 + ii;
      float sreg[4];
#pragma unroll
      for (int u = 0; u < 4; ++u) {
        int j = j0 + jjb + u;
        float acv = st[ii][jjb + u];
        float s;
        if (j <= i) {
          s = (acv + bdf[ii][jjb + u - ii + 31]) * ATT_SCALE;
        } else {
          bool inmem = (i < NMTOK && j < NMTOK) ||
                       (i >= TT - NMTOK && j >= TT - NMTOK);
          if (!inmem) s = -1e30f;
          else if (j == i + 1) s = acv * ATT_SCALE;  // rel_shift zero-pad entry
          else {
            float b2 = 0.f;
            const int rrow = j - i - 2;
            for (int d = 0; d < 64; ++d)
              b2 += bfbits2f(((unsigned int)(ushort_t)qr[ii + 1][d]) << 16) *
                    rm[rrow][d];
            s = (acv + b2) * ATT_SCALE;
          }
        }
        sreg[u] = s;
      }
      float tmax = fmaxf(fmaxf(sreg[0], sreg[1]), fmaxf(sreg[2], sreg[3]));
#pragma unroll
      for (int off = 1; off < 8; off <<= 1) tmax = fmaxf(tmax, __shfl_xor(tmax, off));
      const float mold = m_s[ii];
      const float mnew = fmaxf(mold, tmax);
      const float alpha = __expf(mold - mnew);
      float p[4], psum = 0.f;
#pragma unroll
      for (int u = 0; u < 4; ++u) { p[u] = __expf(sreg[u] - mnew); psum += p[u]; }
#pragma unroll
      for (int off = 1; off < 8; off <<= 1) psum += __shfl_xor(psum, off);
      uint2 pk;
      pk.x = pack2(f2bf(p[0]), f2bf(p[1]));
      pk.y = pack2(f2bf(p[2]), f2bf(p[3]));
      *(uint2*)&pb[ii][jjb] = pk;
      if (g == 0) {
        m_s[ii] = mnew;
        l_s[ii] = l_s[ii] * alpha + psum;
        alpha_s[ii] = alpha;
      }
    }
    barrier_lds();

    {  // ---- phase D: O^T = O^T*alpha + V^T P^T ----
      float a0 = alpha_s[lm], a1 = alpha_s[16 + lm];
      union { bf16x8 v; unsigned int u[4]; } av;
      const unsigned int* vp = (const unsigned int*)&vsT[wv * 16 + lm][quad * 8];
      av.u[0] = vp[0]; av.u[1] = vp[1]; av.u[2] = vp[2]; av.u[3] = vp[3];
      bf16x8 p0 = *(const bf16x8*)&pb[lm][quad * 8];
      bf16x8 p1 = *(const bf16x8*)&pb[16 + lm][quad * 8];
#pragma unroll
      for (int t = 0; t < 4; ++t) { oA[t] *= a0; oB[t] *= a1; }
      oA = __builtin_amdgcn_mfma_f32_16x16x32_bf16(av.v, p0, oA, 0, 0, 0);
      oB = __builtin_amdgcn_mfma_f32_16x16x32_bf16(av.v, p1, oB, 0, 0, 0);
    }
    kcur = knext; v0cur = v0n; v1cur = v1n; band0cur = b0n; band1cur = b1n;
  }

  {  // write partials: m, l (fp32) and un-normalized O (bf16, [i][d] layout)
    const int pidx = (qt * NH + h) * SPLIT + c;
    if (tid < 32) {
      mlP[(size_t)pidx * 64 + tid] = m_s[tid];
      mlP[(size_t)pidx * 64 + 32 + tid] = l_s[tid];
    }
    ushort_t o0[4], o1[4];
#pragma unroll
    for (int t = 0; t < 4; ++t) { o0[t] = f2bf(oA[t]); o1[t] = f2bf(oB[t]); }
    size_t ob = (size_t)pidx * 2048;
    *(uint2*)&opP[ob + (size_t)lm * 64 + wv * 16 + quad * 4] = *(uint2*)o0;
    *(uint2*)&opP[ob + (size_t)(16 + lm) * 64 + wv * 16 + quad * 4] = *(uint2*)o1;
  }
}

// -------- combine <=SPLIT chunk partials -> normalized attn output --------
__global__ __launch_bounds__(256) void k_attn_combine(const float* __restrict__ mlP,
                                                      const ushort_t* __restrict__ opP,
                                                      ushort_t* __restrict__ attnb) {
  const int qt = blockIdx.x, h = blockIdx.y;
  const int nc = (qt + 1 < SPLIT) ? qt + 1 : SPLIT;
  const int tid = threadIdx.x;
  const int i = tid >> 3, d8 = (tid & 7) * 8;
  const size_t base = (size_t)(qt * NH + h) * SPLIT;
  float m[SPLIT], l[SPLIT], wgt[SPLIT];
  float M = -INFINITY;
  for (int cc = 0; cc < nc; ++cc) {
    m[cc] = mlP[(base + cc) * 64 + i];
    l[cc] = mlP[(base + cc) * 64 + 32 + i];
    M = fmaxf(M, m[cc]);
  }
  float L = 0.f;
  for (int cc = 0; cc < nc; ++cc) { wgt[cc] = __expf(m[cc] - M); L += l[cc] * wgt[cc]; }
  float acc[8] = {0, 0, 0, 0, 0, 0, 0, 0};
  for (int cc = 0; cc < nc; ++cc) {
    uint4 v = *(const uint4*)&opP[(base + cc) * 2048 + (size_t)i * 64 + d8];
    float f[8]; unpack8(v, f);
#pragma unroll
    for (int k = 0; k < 8; ++k) acc[k] += wgt[cc] * f[k];
  }
  const float inv = 1.f / L;
  ushort_t o8[8];
#pragma unroll
  for (int k = 0; k < 8; ++k) o8[k] = f2bf(acc[k] * inv);
  *(uint4*)&attnb[(size_t)(qt * 32 + i) * DM + h * DH + d8] = *(uint4*)o8;
}

// ---------------- w = LayerNorm(w + delta) * g + b; writes fp32 + bf16 ----
__global__ __launch_bounds__(256) void k_addln(float* __restrict__ w,
                                               ushort_t* __restrict__ wb,
                                               const float* __restrict__ delta,
                                               const float* __restrict__ gamma,
                                               const float* __restrict__ beta) {
  const int row = blockIdx.x;
  const int tid = threadIdx.x;
  __shared__ float red[4], red2[4];
  size_t base = (size_t)row * DM;
  float x0 = w[base + tid] + delta[base + tid];
  float x1 = w[base + tid + 256] + delta[base + tid + 256];
  float s = x0 + x1;
#pragma unroll
  for (int off = 1; off < 64; off <<= 1) s += __shfl_xor(s, off);
  if ((tid & 63) == 0) red[tid >> 6] = s;
  __syncthreads();
  float mu = (red[0] + red[1] + red[2] + red[3]) * (1.f / 512.f);
  float d0 = x0 - mu, d1 = x1 - mu;
  float v = d0 * d0 + d1 * d1;
#pragma unroll
  for (int off = 1; off < 64; off <<= 1) v += __shfl_xor(v, off);
  if ((tid & 63) == 0) red2[tid >> 6] = v;
  __syncthreads();
  float var = (red2[0] + red2[1] + red2[2] + red2[3]) * (1.f / 512.f);
  float rstd = rsqrtf(var + 1e-5f);
  float o0 = d0 * rstd * gamma[tid] + beta[tid];
  float o1 = d1 * rstd * gamma[tid + 256] + beta[tid + 256];
  w[base + tid] = o0;
  w[base + tid + 256] = o1;
  wb[base + tid] = f2bf(o0);
  wb[base + tid + 256] = f2bf(o1);
}

__global__ __launch_bounds__(256) void k_copy(const float* __restrict__ src,
                                              float* __restrict__ dst) {
  int idx = blockIdx.x * 256 + threadIdx.x;
  if (idx < TT * DM) dst[idx] = src[idx];
}

extern "C" void kernel_launch(void* const* d_in, const int* in_sizes, int n_in,
                              void* d_out, int out_size, void* d_ws, size_t ws_size,
                              hipStream_t stream) {
  const float* we   = (const float*)d_in[0];
  const float* mem  = (const float*)d_in[1];
  const float* Wqkv = (const float*)d_in[2];
  const float* Wr   = (const float*)d_in[3];
  const float* Wo   = (const float*)d_in[4];
  const float* ln1s = (const float*)d_in[5];
  const float* ln1b = (const float*)d_in[6];
  const float* W1   = (const float*)d_in[7];
  const float* b1   = (const float*)d_in[8];
  const float* W2   = (const float*)d_in[9];
  const float* b2   = (const float*)d_in[10];
  const float* ln2s = (const float*)d_in[11];
  const float* ln2b = (const float*)d_in[12];
  const float* rwb  = (const float*)d_in[13];
  const float* rrb  = (const float*)d_in[14];

  // ---- workspace layout (~40 MB) ----
  float* w     = (float*)d_ws;                        // TT*DM fp32
  float* proj  = w + (size_t)TT * DM;                 // TT*DM fp32 (ff2 overlays)
  ushort_t* wb    = (ushort_t*)(proj + (size_t)TT * DM);  // TT*DM bf16
  ushort_t* posb  = wb + (size_t)TT * DM;             // TT*DM bf16
  ushort_t* attnb = posb + (size_t)TT * DM;           // TT*DM bf16
  ushort_t* qkvb  = attnb + (size_t)TT * DM;          // TT*1536 bf16
  ushort_t* rbg   = qkvb + (size_t)TT * QKV_N;        // TT*DM bf16
  ushort_t* WtAll = rbg + (size_t)TT * DM;            // 3407872 shorts: layer's 5 mats
  ushort_t* opP   = WtAll + 3407872;                  // 65*8*4*2048 shorts partial O
  float* mlP   = (float*)(opP + 65 * 8 * SPLIT * 2048);  // 65*8*4*64 floats m/l
  ushort_t* ff1b  = qkvb;                             // TT*DI bf16 overlay
  float* ff2   = proj;
  const size_t OFF_QKVT = 0, OFF_WRT = 786432, OFF_WOT = 1048576,
               OFF_W1T = 1310720, OFF_W2T = 2359296;

  k_build<<<(TT * DM + 255) / 256, 256, 0, stream>>>(we, mem, w, wb, posb);

  dim3 gQKV(QKV_N / 64, 33), gDMg(DM / 64, 33), gDIg(DI / 64, 33);
  dim3 gA(65, NH, SPLIT);
  dim3 gC(65, NH);

  for (int l = 0; l < NLAYER; ++l) {
    k_transpose_all<<<3328, 256, 0, stream>>>(Wqkv, Wr, Wo, W1, W2, WtAll, l);
    k_gemm_mfma<<<gQKV, 256, 0, stream>>>(wb, WtAll + OFF_QKVT, nullptr, nullptr, qkvb,
                                          TT, QKV_N, DM, 4);
    k_gemm_mfma<<<gDMg, 256, 0, stream>>>(posb, WtAll + OFF_WRT, nullptr, nullptr, rbg,
                                          TT, DM, DM, 4);
    k_attn<<<gA, 256, 0, stream>>>(qkvb, rbg, rwb, rrb, mlP, opP);
    k_attn_combine<<<gC, 256, 0, stream>>>(mlP, opP, attnb);
    k_gemm_mfma<<<gDMg, 256, 0, stream>>>(attnb, WtAll + OFF_WOT, nullptr, proj, nullptr,
                                          TT, DM, DM, 0);
    k_addln<<<TT, 256, 0, stream>>>(w, wb, proj, ln1s + (size_t)l * DM, ln1b + (size_t)l * DM);
    k_gemm_mfma<<<gDIg, 256, 0, stream>>>(wb, WtAll + OFF_W1T, b1 + (size_t)l * DI, nullptr, ff1b,
                                          TT, DI, DM, 1 | 2 | 4);
    k_gemm_mfma<<<gDMg, 256, 0, stream>>>(ff1b, WtAll + OFF_W2T, b2 + (size_t)l * DM, ff2, nullptr,
                                          TT, DM, DI, 1);
    k_addln<<<TT, 256, 0, stream>>>(w, wb, ff2, ln2s + (size_t)l * DM, ln2b + (size_t)l * DM);
  }
  k_copy<<<(TT * DM + 255) / 256, 256, 0, stream>>>(w, (float*)d_out);
}

// Round 8
// 730.328 us; speedup vs baseline: 1.4269x; 1.2807x over previous
//
#include <hip/hip_runtime.h>
#include <hip/hip_bf16.h>
#include <math.h>

#define TT 2080
#define DM 512
#define DI 2048
#define NH 8
#define DH 64
#define NMTOK 16
#define NLAYER 4
#define QKV_N 1536
#define ATT_SCALE 0.125f
#define SPLIT 8

typedef short bf16x8 __attribute__((ext_vector_type(8)));
typedef float f32x4 __attribute__((ext_vector_type(4)));
typedef unsigned short ushort_t;

__device__ __forceinline__ ushort_t f2bf(float f) {
  __hip_bfloat16 h = __float2bfloat16(f);
  return *reinterpret_cast<ushort_t*>(&h);
}
__device__ __forceinline__ float bfbits2f(unsigned int hi_bits) {
  return __uint_as_float(hi_bits);
}
__device__ __forceinline__ void unpack8(uint4 v, float* f) {
  f[0] = bfbits2f(v.x << 16); f[1] = bfbits2f(v.x & 0xffff0000u);
  f[2] = bfbits2f(v.y << 16); f[3] = bfbits2f(v.y & 0xffff0000u);
  f[4] = bfbits2f(v.z << 16); f[5] = bfbits2f(v.z & 0xffff0000u);
  f[6] = bfbits2f(v.w << 16); f[7] = bfbits2f(v.w & 0xffff0000u);
}
__device__ __forceinline__ unsigned int pack2(ushort_t lo, ushort_t hi) {
  return (unsigned int)lo | ((unsigned int)hi << 16);
}
// Barrier draining LDS ops only — leaves global (vmcnt) loads in flight.
__device__ __forceinline__ void barrier_lds() {
  asm volatile("s_waitcnt lgkmcnt(0)" ::: "memory");
  __builtin_amdgcn_s_barrier();
}

// ---------------- build w (fp32+bf16) and pos_emb (bf16) ------------------
__global__ __launch_bounds__(256) void k_build(const float* __restrict__ we,
                                               const float* __restrict__ mem,
                                               float* __restrict__ w,
                                               ushort_t* __restrict__ wb,
                                               ushort_t* __restrict__ posb) {
  int idx = blockIdx.x * 256 + threadIdx.x;
  if (idx >= TT * DM) return;
  int t = idx >> 9, d = idx & 511;
  float v;
  if (t < NMTOK) v = mem[t * DM + d];
  else if (t < NMTOK + 2048) v = we[(t - NMTOK) * DM + d];
  else v = mem[(t - (NMTOK + 2048)) * DM + d];
  w[idx] = v;
  wb[idx] = f2bf(v);
  float p = (float)(TT - 1 - t);
  int i2 = d & 255;
  float freq = 1.0f / powf(10000.f, ((float)(2 * i2)) / 512.f);
  float ang = p * freq;
  posb[idx] = f2bf((d < 256) ? sinf(ang) : cosf(ang));
}

// ---- batched transpose+cast of all 5 weight mats of one layer ------------
__global__ __launch_bounds__(256) void k_transpose_all(
    const float* __restrict__ Wqkv, const float* __restrict__ Wr,
    const float* __restrict__ Wo, const float* __restrict__ W1,
    const float* __restrict__ W2, ushort_t* __restrict__ dstAll, int l) {
  __shared__ float t[32][33];
  const int tid = threadIdx.x;
  int idx = blockIdx.x;
  const float* src;
  ushort_t* dst;
  int K, N, local;
  if (idx < 768)       { src = Wqkv + (size_t)l * 512 * 1536; dst = dstAll;          K = 512;  N = 1536; local = idx; }
  else if (idx < 1024) { src = Wr   + (size_t)l * 512 * 512;  dst = dstAll + 786432; K = 512;  N = 512;  local = idx - 768; }
  else if (idx < 1280) { src = Wo   + (size_t)l * 512 * 512;  dst = dstAll + 1048576; K = 512; N = 512;  local = idx - 1024; }
  else if (idx < 2304) { src = W1   + (size_t)l * 512 * 2048; dst = dstAll + 1310720; K = 512; N = 2048; local = idx - 1280; }
  else                 { src = W2   + (size_t)l * 2048 * 512; dst = dstAll + 2359296; K = 2048; N = 512; local = idx - 2304; }
  const int ntiles = N / 32;
  const int n0 = (local % ntiles) * 32, k0 = (local / ntiles) * 32;
#pragma unroll
  for (int p = 0; p < 4; ++p) {
    int row = (tid >> 5) + 8 * p, col = tid & 31;
    t[row][col] = src[(size_t)(k0 + row) * N + n0 + col];
  }
  __syncthreads();
#pragma unroll
  for (int p = 0; p < 4; ++p) {
    int n = (tid >> 5) + 8 * p, k = tid & 31;
    dst[(size_t)(n0 + n) * K + k0 + k] = f2bf(t[k][n]);
  }
}

// -------- bf16 MFMA GEMM body, 32x64 tile (M=2080 fixed, 65 m-tiles) ------
// flags: 1=+bias, 2=relu, 4=bf16 output (else fp32)
__device__ __forceinline__ void gemm32x64_body(const ushort_t* __restrict__ A,
                                               const ushort_t* __restrict__ Bt,
                                               const float* __restrict__ bias,
                                               float* __restrict__ C,
                                               ushort_t* __restrict__ Cb,
                                               int N, int K, int flags,
                                               int m0, int n0) {
  __shared__ short As[32][72];
  __shared__ short Bs[64][72];
  const int tid = threadIdx.x;
  const int lane = tid & 63, wv = tid >> 6;
  const int wm = (wv >> 1) * 16, wn = (wv & 1) * 32;
  const int lm = lane & 15, quad = lane >> 4;
  const int sr = tid >> 3, sc8 = (tid & 7) * 8;

  f32x4 acc[2];
  acc[0] = (f32x4)(0.f); acc[1] = (f32x4)(0.f);

  auto loadA = [&](int k0) -> uint4 {
    return *(const uint4*)&A[(size_t)(m0 + sr) * K + k0 + sc8];
  };
  auto loadB = [&](int row, int k0) -> uint4 {
    return *(const uint4*)&Bt[(size_t)(n0 + row) * K + k0 + sc8];
  };

  uint4 ac_ = loadA(0);
  uint4 b0c = loadB(sr, 0), b1c = loadB(sr + 32, 0);

  for (int k0 = 0; k0 < K; k0 += 64) {
    const int kn = (k0 + 64 < K) ? k0 + 64 : k0;  // clamped reload on last iter
    uint4 an = loadA(kn);
    uint4 b0n = loadB(sr, kn), b1n = loadB(sr + 32, kn);
    barrier_lds();  // prev ds_reads done; prefetch stays in flight
    *(uint4*)&As[sr][sc8] = ac_;
    *(uint4*)&Bs[sr][sc8] = b0c;
    *(uint4*)&Bs[sr + 32][sc8] = b1c;
    barrier_lds();
#pragma unroll
    for (int kk = 0; kk < 64; kk += 32) {
      bf16x8 a = *(const bf16x8*)&As[wm + lm][kk + quad * 8];
      bf16x8 b0 = *(const bf16x8*)&Bs[wn + lm][kk + quad * 8];
      bf16x8 b1 = *(const bf16x8*)&Bs[wn + 16 + lm][kk + quad * 8];
      acc[0] = __builtin_amdgcn_mfma_f32_16x16x32_bf16(a, b0, acc[0], 0, 0, 0);
      acc[1] = __builtin_amdgcn_mfma_f32_16x16x32_bf16(a, b1, acc[1], 0, 0, 0);
    }
    ac_ = an; b0c = b0n; b1c = b1n;
  }
#pragma unroll
  for (int nt = 0; nt < 2; ++nt) {
    int col = n0 + wn + nt * 16 + lm;
    float bv = (flags & 1) ? bias[col] : 0.f;
#pragma unroll
    for (int t = 0; t < 4; ++t) {
      int row = m0 + wm + quad * 4 + t;
      float v = acc[nt][t] + bv;
      if (flags & 2) v = fmaxf(v, 0.f);
      if (flags & 4) Cb[(size_t)row * N + col] = f2bf(v);
      else C[(size_t)row * N + col] = v;
    }
  }
}

__global__ __launch_bounds__(256) void k_gemm_mfma(const ushort_t* __restrict__ A,
                                                   const ushort_t* __restrict__ Bt,
                                                   const float* __restrict__ bias,
                                                   float* __restrict__ C,
                                                   ushort_t* __restrict__ Cb,
                                                   int N, int K, int flags) {
  gemm32x64_body(A, Bt, bias, C, Cb, N, K, flags, blockIdx.y * 32, blockIdx.x * 64);
}

// merged QKV + Wr GEMMs (independent, same shapes family) in one dispatch
__global__ __launch_bounds__(256) void k_gemm_qkvwr(const ushort_t* __restrict__ wb,
                                                    const ushort_t* __restrict__ posb,
                                                    const ushort_t* __restrict__ qkvT,
                                                    const ushort_t* __restrict__ wrT,
                                                    ushort_t* __restrict__ qkvb,
                                                    ushort_t* __restrict__ rbg) {
  const int bx = blockIdx.x;
  if (bx < 24)
    gemm32x64_body(wb, qkvT, nullptr, nullptr, qkvb, QKV_N, DM, 4,
                   blockIdx.y * 32, bx * 64);
  else
    gemm32x64_body(posb, wrT, nullptr, nullptr, rbg, DM, DM, 4,
                   blockIdx.y * 32, (bx - 24) * 64);
}

// ------- MFMA flash attention, split-j partials (flash split-K style) -----
// Chunk c handles jt = c, c+SPLIT, ... <= qt. Emits partial O (un-normalized,
// bf16, O[i][d] layout), m, l. Combine kernel merges the <=SPLIT chunks.
__global__ __launch_bounds__(256) void k_attn(const ushort_t* __restrict__ qkv,
                                              const ushort_t* __restrict__ r,
                                              const float* __restrict__ rwb,
                                              const float* __restrict__ rrb,
                                              float* __restrict__ mlP,
                                              ushort_t* __restrict__ opP) {
  const int h = blockIdx.y;
  const int qt = 64 - blockIdx.x;  // heavy q-tiles dispatch first
  const int c = blockIdx.z;
  if (c > qt) return;  // empty chunk
  const int i0 = qt * 32;
  const int tid = threadIdx.x;
  const int lane = tid & 63, wv = tid >> 6;
  const int lm = lane & 15, quad = lane >> 4;

  __shared__ short qw[32][72];     // (q+rwb) bf16 [i][d]
  __shared__ short qr[33][72];     // (q+rrb) bf16 [i][d]
  __shared__ short ks_[32][72];    // K tile [j][d]
  __shared__ short vsT[64][70];    // V^T [d][j]
  __shared__ short rband[64][72];  // r band [t][d], kidx = kb + t
  __shared__ short pb[32][40];     // P bf16 [i][j]
  __shared__ float rm[14][68];     // r rows 0..13 fp32 (mem-block wrap)
  __shared__ float st[32][33];     // AC fp32 [i][j]
  __shared__ float bdf[32][66];    // BDfull fp32 [i][t]
  __shared__ float m_s[32], l_s[32], alpha_s[32];

  const uint4 zero4 = make_uint4(0, 0, 0, 0);
  const int krr = tid >> 3, kc8 = (tid & 7) * 8;  // K/rband staging coords
  const int vrr = tid >> 4, vc4 = tid & 15;       // V staging coords
  const int kb0 = TT - 32 - i0;

  auto loadK = [&](int j0) -> uint4 {
    return *(const uint4*)&qkv[(size_t)(j0 + krr) * QKV_N + DM + h * DH + kc8];
  };
  auto loadBand = [&](int kidx) -> uint4 {
    return (kidx < TT) ? *(const uint4*)&r[(size_t)kidx * DM + h * DH + kc8]
                       : zero4;
  };

  {  // stage qw/qr with bias add
    int rr = tid >> 3, c8 = (tid & 7) * 8;
    uint4 qv = *(const uint4*)&qkv[(size_t)(i0 + rr) * QKV_N + h * DH + c8];
    float f[8]; unpack8(qv, f);
    float4 w0 = *(const float4*)&rwb[h * DH + c8];
    float4 w1 = *(const float4*)&rwb[h * DH + c8 + 4];
    float4 r0 = *(const float4*)&rrb[h * DH + c8];
    float4 r1 = *(const float4*)&rrb[h * DH + c8 + 4];
    uint4 ow, orr;
    ow.x = pack2(f2bf(f[0] + w0.x), f2bf(f[1] + w0.y));
    ow.y = pack2(f2bf(f[2] + w0.z), f2bf(f[3] + w0.w));
    ow.z = pack2(f2bf(f[4] + w1.x), f2bf(f[5] + w1.y));
    ow.w = pack2(f2bf(f[6] + w1.z), f2bf(f[7] + w1.w));
    orr.x = pack2(f2bf(f[0] + r0.x), f2bf(f[1] + r0.y));
    orr.y = pack2(f2bf(f[2] + r0.z), f2bf(f[3] + r0.w));
    orr.z = pack2(f2bf(f[4] + r1.x), f2bf(f[5] + r1.y));
    orr.w = pack2(f2bf(f[6] + r1.z), f2bf(f[7] + r1.w));
    *(uint4*)&qw[rr][c8] = ow;
    *(uint4*)&qr[rr][c8] = orr;
  }
  if (tid < 112) {  // rm staging (fp32)
    int rr = tid >> 3, c8 = (tid & 7) * 8;
    uint4 v = *(const uint4*)&r[(size_t)rr * DM + h * DH + c8];
    float f[8]; unpack8(v, f);
#pragma unroll
    for (int j = 0; j < 8; ++j) rm[rr][c8 + j] = f[j];
  }
  if (tid < 32) { m_s[tid] = -INFINITY; l_s[tid] = 0.f; }

  f32x4 oA = (f32x4)(0.f);  // O^T accum, d-tile=wv, i = i0+lm
  f32x4 oB = (f32x4)(0.f);  // i = i0+16+lm

  // ---- pipeline prologue: first chunk tile into registers ----
  uint4 kcur = loadK(c * 32);
  const ushort_t* vp0 = &qkv[(size_t)(c * 32 + 2 * vrr) * QKV_N + 2 * DM + h * DH + vc4 * 4];
  uint2 v0cur = *(const uint2*)vp0, v1cur = *(const uint2*)(vp0 + QKV_N);
  uint4 band0cur = loadBand(kb0 + 32 * c + krr);
  uint4 band1cur = loadBand(kb0 + 32 * c + 32 + krr);

  for (int jt = c; jt <= qt; jt += SPLIT) {
    const int j0 = jt * 32;
    // ---- issue next tile's loads (clamped reload on last iteration) ----
    const int jn = (jt + SPLIT <= qt) ? jt + SPLIT : jt;
    uint4 knext = loadK(jn * 32);
    const ushort_t* vpn = &qkv[(size_t)(jn * 32 + 2 * vrr) * QKV_N + 2 * DM + h * DH + vc4 * 4];
    uint2 v0n = *(const uint2*)vpn, v1n = *(const uint2*)(vpn + QKV_N);
    uint4 b0n = loadBand(kb0 + 32 * jn + krr);
    uint4 b1n = loadBand(kb0 + 32 * jn + 32 + krr);

    barrier_lds();  // prior iteration's ds ops done; vmcnt stays in flight
    // ---- write current tile (loaded last iteration) to LDS ----
    *(uint4*)&ks_[krr][kc8] = kcur;
    {
      ushort_t a0 = (ushort_t)(v0cur.x & 0xffffu), a1 = (ushort_t)(v0cur.x >> 16);
      ushort_t a2 = (ushort_t)(v0cur.y & 0xffffu), a3 = (ushort_t)(v0cur.y >> 16);
      ushort_t c0 = (ushort_t)(v1cur.x & 0xffffu), c1 = (ushort_t)(v1cur.x >> 16);
      ushort_t c2 = (ushort_t)(v1cur.y & 0xffffu), c3 = (ushort_t)(v1cur.y >> 16);
      *(unsigned int*)&vsT[vc4 * 4 + 0][2 * vrr] = pack2(a0, c0);
      *(unsigned int*)&vsT[vc4 * 4 + 1][2 * vrr] = pack2(a1, c1);
      *(unsigned int*)&vsT[vc4 * 4 + 2][2 * vrr] = pack2(a2, c2);
      *(unsigned int*)&vsT[vc4 * 4 + 3][2 * vrr] = pack2(a3, c3);
    }
    *(uint4*)&rband[krr][kc8] = band0cur;
    *(uint4*)&rband[krr + 32][kc8] = band1cur;
    barrier_lds();

    {  // ---- phase B: AC + BDfull MFMAs -> LDS ----
      const int acit = wv >> 1, acjt = wv & 1;
      f32x4 ac = (f32x4)(0.f);
#pragma unroll
      for (int k2 = 0; k2 < 64; k2 += 32) {
        bf16x8 a = *(const bf16x8*)&qw[acit * 16 + lm][k2 + quad * 8];
        bf16x8 b = *(const bf16x8*)&ks_[acjt * 16 + lm][k2 + quad * 8];
        ac = __builtin_amdgcn_mfma_f32_16x16x32_bf16(a, b, ac, 0, 0, 0);
      }
#pragma unroll
      for (int t = 0; t < 4; ++t)
        st[acit * 16 + quad * 4 + t][acjt * 16 + lm] = ac[t];

      const int brt = wv >> 1, bc0 = wv & 1, bc1 = (wv & 1) + 2;
      f32x4 bd0 = (f32x4)(0.f), bd1 = (f32x4)(0.f);
#pragma unroll
      for (int k2 = 0; k2 < 64; k2 += 32) {
        bf16x8 a = *(const bf16x8*)&qr[brt * 16 + lm][k2 + quad * 8];
        bf16x8 b0 = *(const bf16x8*)&rband[bc0 * 16 + lm][k2 + quad * 8];
        bf16x8 b1 = *(const bf16x8*)&rband[bc1 * 16 + lm][k2 + quad * 8];
        bd0 = __builtin_amdgcn_mfma_f32_16x16x32_bf16(a, b0, bd0, 0, 0, 0);
        bd1 = __builtin_amdgcn_mfma_f32_16x16x32_bf16(a, b1, bd1, 0, 0, 0);
      }
#pragma unroll
      for (int t = 0; t < 4; ++t) {
        bdf[brt * 16 + quad * 4 + t][bc0 * 16 + lm] = bd0[t];
        bdf[brt * 16 + quad * 4 + t][bc1 * 16 + lm] = bd1[t];
      }
    }
    barrier_lds();

    {  // ---- phase C: score assembly + online softmax ----
      const int ii = tid >> 3, g = tid & 7, jjb = g * 4;
      const int i = i0 + ii;
      float sreg[4];
#pragma unroll
      for (int u = 0; u < 4; ++u) {
        int j = j0 + jjb + u;
        float acv = st[ii][jjb + u];
        float s;
        if (j <= i) {
          s = (acv + bdf[ii][jjb + u - ii + 31]) * ATT_SCALE;
        } else {
          bool inmem = (i < NMTOK && j < NMTOK) ||
                       (i >= TT - NMTOK && j >= TT - NMTOK);
          if (!inmem) s = -1e30f;
          else if (j == i + 1) s = acv * ATT_SCALE;  // rel_shift zero-pad entry
          else {
            float b2 = 0.f;
            const int rrow = j - i - 2;
            for (int d = 0; d < 64; ++d)
              b2 += bfbits2f(((unsigned int)(ushort_t)qr[ii + 1][d]) << 16) *
                    rm[rrow][d];
            s = (acv + b2) * ATT_SCALE;
          }
        }
        sreg[u] = s;
      }
      float tmax = fmaxf(fmaxf(sreg[0], sreg[1]), fmaxf(sreg[2], sreg[3]));
#pragma unroll
      for (int off = 1; off < 8; off <<= 1) tmax = fmaxf(tmax, __shfl_xor(tmax, off));
      const float mold = m_s[ii];
      const float mnew = fmaxf(mold, tmax);
      const float alpha = __expf(mold - mnew);
      float p[4], psum = 0.f;
#pragma unroll
      for (int u = 0; u < 4; ++u) { p[u] = __expf(sreg[u] - mnew); psum += p[u]; }
#pragma unroll
      for (int off = 1; off < 8; off <<= 1) psum += __shfl_xor(psum, off);
      uint2 pk;
      pk.x = pack2(f2bf(p[0]), f2bf(p[1]));
      pk.y = pack2(f2bf(p[2]), f2bf(p[3]));
      *(uint2*)&pb[ii][jjb] = pk;
      if (g == 0) {
        m_s[ii] = mnew;
        l_s[ii] = l_s[ii] * alpha + psum;
        alpha_s[ii] = alpha;
      }
    }
    barrier_lds();

    {  // ---- phase D: O^T = O^T*alpha + V^T P^T ----
      float a0 = alpha_s[lm], a1 = alpha_s[16 + lm];
      union { bf16x8 v; unsigned int u[4]; } av;
      const unsigned int* vp = (const unsigned int*)&vsT[wv * 16 + lm][quad * 8];
      av.u[0] = vp[0]; av.u[1] = vp[1]; av.u[2] = vp[2]; av.u[3] = vp[3];
      bf16x8 p0 = *(const bf16x8*)&pb[lm][quad * 8];
      bf16x8 p1 = *(const bf16x8*)&pb[16 + lm][quad * 8];
#pragma unroll
      for (int t = 0; t < 4; ++t) { oA[t] *= a0; oB[t] *= a1; }
      oA = __builtin_amdgcn_mfma_f32_16x16x32_bf16(av.v, p0, oA, 0, 0, 0);
      oB = __builtin_amdgcn_mfma_f32_16x16x32_bf16(av.v, p1, oB, 0, 0, 0);
    }
    kcur = knext; v0cur = v0n; v1cur = v1n; band0cur = b0n; band1cur = b1n;
  }

  {  // write partials: m, l (fp32) and un-normalized O (bf16, [i][d] layout)
    const int pidx = (qt * NH + h) * SPLIT + c;
    if (tid < 32) {
      mlP[(size_t)pidx * 64 + tid] = m_s[tid];
      mlP[(size_t)pidx * 64 + 32 + tid] = l_s[tid];
    }
    ushort_t o0[4], o1[4];
#pragma unroll
    for (int t = 0; t < 4; ++t) { o0[t] = f2bf(oA[t]); o1[t] = f2bf(oB[t]); }
    size_t ob = (size_t)pidx * 2048;
    *(uint2*)&opP[ob + (size_t)lm * 64 + wv * 16 + quad * 4] = *(uint2*)o0;
    *(uint2*)&opP[ob + (size_t)(16 + lm) * 64 + wv * 16 + quad * 4] = *(uint2*)o1;
  }
}

// -------- combine <=SPLIT chunk partials -> normalized attn output --------
__global__ __launch_bounds__(256) void k_attn_combine(const float* __restrict__ mlP,
                                                      const ushort_t* __restrict__ opP,
                                                      ushort_t* __restrict__ attnb) {
  const int qt = blockIdx.x, h = blockIdx.y;
  const int nc = (qt + 1 < SPLIT) ? qt + 1 : SPLIT;
  const int tid = threadIdx.x;
  const int i = tid >> 3, d8 = (tid & 7) * 8;
  const size_t base = (size_t)(qt * NH + h) * SPLIT;
  float m[SPLIT], l[SPLIT], wgt[SPLIT];
  float M = -INFINITY;
  for (int cc = 0; cc < nc; ++cc) {
    m[cc] = mlP[(base + cc) * 64 + i];
    l[cc] = mlP[(base + cc) * 64 + 32 + i];
    M = fmaxf(M, m[cc]);
  }
  float L = 0.f;
  for (int cc = 0; cc < nc; ++cc) { wgt[cc] = __expf(m[cc] - M); L += l[cc] * wgt[cc]; }
  float acc[8] = {0, 0, 0, 0, 0, 0, 0, 0};
  for (int cc = 0; cc < nc; ++cc) {
    uint4 v = *(const uint4*)&opP[(base + cc) * 2048 + (size_t)i * 64 + d8];
    float f[8]; unpack8(v, f);
#pragma unroll
    for (int k = 0; k < 8; ++k) acc[k] += wgt[cc] * f[k];
  }
  const float inv = 1.f / L;
  ushort_t o8[8];
#pragma unroll
  for (int k = 0; k < 8; ++k) o8[k] = f2bf(acc[k] * inv);
  *(uint4*)&attnb[(size_t)(qt * 32 + i) * DM + h * DH + d8] = *(uint4*)o8;
}

// ---------------- w = LayerNorm(w + delta) * g + b; writes fp32 + bf16 ----
__global__ __launch_bounds__(256) void k_addln(float* __restrict__ w,
                                               ushort_t* __restrict__ wb,
                                               const float* __restrict__ delta,
                                               const float* __restrict__ gamma,
                                               const float* __restrict__ beta) {
  const int row = blockIdx.x;
  const int tid = threadIdx.x;
  __shared__ float red[4], red2[4];
  size_t base = (size_t)row * DM;
  float x0 = w[base + tid] + delta[base + tid];
  float x1 = w[base + tid + 256] + delta[base + tid + 256];
  float s = x0 + x1;
#pragma unroll
  for (int off = 1; off < 64; off <<= 1) s += __shfl_xor(s, off);
  if ((tid & 63) == 0) red[tid >> 6] = s;
  __syncthreads();
  float mu = (red[0] + red[1] + red[2] + red[3]) * (1.f / 512.f);
  float d0 = x0 - mu, d1 = x1 - mu;
  float v = d0 * d0 + d1 * d1;
#pragma unroll
  for (int off = 1; off < 64; off <<= 1) v += __shfl_xor(v, off);
  if ((tid & 63) == 0) red2[tid >> 6] = v;
  __syncthreads();
  float var = (red2[0] + red2[1] + red2[2] + red2[3]) * (1.f / 512.f);
  float rstd = rsqrtf(var + 1e-5f);
  float o0 = d0 * rstd * gamma[tid] + beta[tid];
  float o1 = d1 * rstd * gamma[tid + 256] + beta[tid + 256];
  w[base + tid] = o0;
  w[base + tid + 256] = o1;
  wb[base + tid] = f2bf(o0);
  wb[base + tid + 256] = f2bf(o1);
}

__global__ __launch_bounds__(256) void k_copy(const float* __restrict__ src,
                                              float* __restrict__ dst) {
  int idx = blockIdx.x * 256 + threadIdx.x;
  if (idx < TT * DM) dst[idx] = src[idx];
}

extern "C" void kernel_launch(void* const* d_in, const int* in_sizes, int n_in,
                              void* d_out, int out_size, void* d_ws, size_t ws_size,
                              hipStream_t stream) {
  const float* we   = (const float*)d_in[0];
  const float* mem  = (const float*)d_in[1];
  const float* Wqkv = (const float*)d_in[2];
  const float* Wr   = (const float*)d_in[3];
  const float* Wo   = (const float*)d_in[4];
  const float* ln1s = (const float*)d_in[5];
  const float* ln1b = (const float*)d_in[6];
  const float* W1   = (const float*)d_in[7];
  const float* b1   = (const float*)d_in[8];
  const float* W2   = (const float*)d_in[9];
  const float* b2   = (const float*)d_in[10];
  const float* ln2s = (const float*)d_in[11];
  const float* ln2b = (const float*)d_in[12];
  const float* rwb  = (const float*)d_in[13];
  const float* rrb  = (const float*)d_in[14];

  // ---- workspace layout (~49 MB) ----
  float* w     = (float*)d_ws;                        // TT*DM fp32
  float* proj  = w + (size_t)TT * DM;                 // TT*DM fp32 (ff2 overlays)
  ushort_t* wb    = (ushort_t*)(proj + (size_t)TT * DM);  // TT*DM bf16
  ushort_t* posb  = wb + (size_t)TT * DM;             // TT*DM bf16
  ushort_t* attnb = posb + (size_t)TT * DM;           // TT*DM bf16
  ushort_t* qkvb  = attnb + (size_t)TT * DM;          // TT*1536 bf16
  ushort_t* rbg   = qkvb + (size_t)TT * QKV_N;        // TT*DM bf16
  ushort_t* WtAll = rbg + (size_t)TT * DM;            // 3407872 shorts: layer's 5 mats
  ushort_t* opP   = WtAll + 3407872;                  // 65*8*SPLIT*2048 shorts partial O
  float* mlP   = (float*)(opP + (size_t)65 * 8 * SPLIT * 2048);  // 65*8*SPLIT*64 f32
  ushort_t* ff1b  = qkvb;                             // TT*DI bf16 overlay
  float* ff2   = proj;
  const size_t OFF_QKVT = 0, OFF_WRT = 786432, OFF_WOT = 1048576,
               OFF_W1T = 1310720, OFF_W2T = 2359296;

  k_build<<<(TT * DM + 255) / 256, 256, 0, stream>>>(we, mem, w, wb, posb);

  dim3 gQW(32, 65);          // merged QKV (24 n-tiles) + Wr (8 n-tiles)
  dim3 gDM32(DM / 64, 65);   // Wo / W2
  dim3 gDI32(DI / 64, 65);   // W1
  dim3 gA(65, NH, SPLIT);
  dim3 gC(65, NH);

  for (int l = 0; l < NLAYER; ++l) {
    k_transpose_all<<<3328, 256, 0, stream>>>(Wqkv, Wr, Wo, W1, W2, WtAll, l);
    k_gemm_qkvwr<<<gQW, 256, 0, stream>>>(wb, posb, WtAll + OFF_QKVT,
                                          WtAll + OFF_WRT, qkvb, rbg);
    k_attn<<<gA, 256, 0, stream>>>(qkvb, rbg, rwb, rrb, mlP, opP);
    k_attn_combine<<<gC, 256, 0, stream>>>(mlP, opP, attnb);
    k_gemm_mfma<<<gDM32, 256, 0, stream>>>(attnb, WtAll + OFF_WOT, nullptr, proj, nullptr,
                                           DM, DM, 0);
    k_addln<<<TT, 256, 0, stream>>>(w, wb, proj, ln1s + (size_t)l * DM, ln1b + (size_t)l * DM);
    k_gemm_mfma<<<gDI32, 256, 0, stream>>>(wb, WtAll + OFF_W1T, b1 + (size_t)l * DI, nullptr, ff1b,
                                           DI, DM, 1 | 2 | 4);
    k_gemm_mfma<<<gDM32, 256, 0, stream>>>(ff1b, WtAll + OFF_W2T, b2 + (size_t)l * DM, ff2, nullptr,
                                           DM, DI, 1);
    k_addln<<<TT, 256, 0, stream>>>(w, wb, ff2, ln2s + (size_t)l * DM, ln2b + (size_t)l * DM);
  }
  k_copy<<<(TT * DM + 255) / 256, 256, 0, stream>>>(w, (float*)d_out);
}

// Round 9
// 729.989 us; speedup vs baseline: 1.4275x; 1.0005x over previous
//
#include <hip/hip_runtime.h>
#include <hip/hip_bf16.h>
#include <math.h>

#define TT 2080
#define DM 512
#define DI 2048
#define NH 8
#define DH 64
#define NMTOK 16
#define NLAYER 4
#define QKV_N 1536
#define ATT_SCALE 0.125f
#define SPLIT 8
#define WT_STRIDE 3407872  // shorts per layer's transposed-weight block

typedef short bf16x8 __attribute__((ext_vector_type(8)));
typedef float f32x4 __attribute__((ext_vector_type(4)));
typedef unsigned short ushort_t;

__device__ __forceinline__ ushort_t f2bf(float f) {
  __hip_bfloat16 h = __float2bfloat16(f);
  return *reinterpret_cast<ushort_t*>(&h);
}
__device__ __forceinline__ float bfbits2f(unsigned int hi_bits) {
  return __uint_as_float(hi_bits);
}
__device__ __forceinline__ void unpack8(uint4 v, float* f) {
  f[0] = bfbits2f(v.x << 16); f[1] = bfbits2f(v.x & 0xffff0000u);
  f[2] = bfbits2f(v.y << 16); f[3] = bfbits2f(v.y & 0xffff0000u);
  f[4] = bfbits2f(v.z << 16); f[5] = bfbits2f(v.z & 0xffff0000u);
  f[6] = bfbits2f(v.w << 16); f[7] = bfbits2f(v.w & 0xffff0000u);
}
__device__ __forceinline__ unsigned int pack2(ushort_t lo, ushort_t hi) {
  return (unsigned int)lo | ((unsigned int)hi << 16);
}
// Barrier draining LDS ops only — leaves global (vmcnt) loads in flight.
__device__ __forceinline__ void barrier_lds() {
  asm volatile("s_waitcnt lgkmcnt(0)" ::: "memory");
  __builtin_amdgcn_s_barrier();
}

// ---- fused prep: all 4 layers' weight transposes + build w/pos ------------
// blocks [0, 4*3328): transpose; blocks [13312, 13312+4160): build
__global__ __launch_bounds__(256) void k_prep(
    const float* __restrict__ Wqkv, const float* __restrict__ Wr,
    const float* __restrict__ Wo, const float* __restrict__ W1,
    const float* __restrict__ W2, ushort_t* __restrict__ dstAll,
    const float* __restrict__ we, const float* __restrict__ mem,
    float* __restrict__ w, ushort_t* __restrict__ wb,
    ushort_t* __restrict__ posb) {
  const int tid = threadIdx.x;
  if (blockIdx.x >= 13312) {  // ---- build ----
    int idx = (blockIdx.x - 13312) * 256 + tid;
    if (idx >= TT * DM) return;
    int t = idx >> 9, d = idx & 511;
    float v;
    if (t < NMTOK) v = mem[t * DM + d];
    else if (t < NMTOK + 2048) v = we[(t - NMTOK) * DM + d];
    else v = mem[(t - (NMTOK + 2048)) * DM + d];
    w[idx] = v;
    wb[idx] = f2bf(v);
    float p = (float)(TT - 1 - t);
    int i2 = d & 255;
    float freq = 1.0f / powf(10000.f, ((float)(2 * i2)) / 512.f);
    float ang = p * freq;
    posb[idx] = f2bf((d < 256) ? sinf(ang) : cosf(ang));
    return;
  }
  // ---- transpose+cast, layer l ----
  __shared__ float tl[32][33];
  const int l = blockIdx.x / 3328;
  int idx = blockIdx.x % 3328;
  const float* src;
  ushort_t* dst = dstAll + (size_t)l * WT_STRIDE;
  int K, N, local;
  if (idx < 768)       { src = Wqkv + (size_t)l * 512 * 1536; K = 512;  N = 1536; local = idx; }
  else if (idx < 1024) { src = Wr   + (size_t)l * 512 * 512;  dst += 786432;  K = 512;  N = 512;  local = idx - 768; }
  else if (idx < 1280) { src = Wo   + (size_t)l * 512 * 512;  dst += 1048576; K = 512;  N = 512;  local = idx - 1024; }
  else if (idx < 2304) { src = W1   + (size_t)l * 512 * 2048; dst += 1310720; K = 512;  N = 2048; local = idx - 1280; }
  else                 { src = W2   + (size_t)l * 2048 * 512; dst += 2359296; K = 2048; N = 512;  local = idx - 2304; }
  const int ntiles = N / 32;
  const int n0 = (local % ntiles) * 32, k0 = (local / ntiles) * 32;
#pragma unroll
  for (int p = 0; p < 4; ++p) {
    int row = (tid >> 5) + 8 * p, col = tid & 31;
    tl[row][col] = src[(size_t)(k0 + row) * N + n0 + col];
  }
  __syncthreads();
#pragma unroll
  for (int p = 0; p < 4; ++p) {
    int n = (tid >> 5) + 8 * p, k = tid & 31;
    dst[(size_t)(n0 + n) * K + k0 + k] = f2bf(tl[k][n]);
  }
}

// -------- bf16 MFMA GEMM body, 32x64 tile, 2-deep register prefetch -------
// flags: 1=+bias, 2=relu, 4=bf16 output (else fp32)
__device__ __forceinline__ void gemm32x64_body(const ushort_t* __restrict__ A,
                                               const ushort_t* __restrict__ Bt,
                                               const float* __restrict__ bias,
                                               float* __restrict__ C,
                                               ushort_t* __restrict__ Cb,
                                               int N, int K, int flags,
                                               int m0, int n0) {
  __shared__ short As[32][72];
  __shared__ short Bs[64][72];
  const int tid = threadIdx.x;
  const int lane = tid & 63, wv = tid >> 6;
  const int wm = (wv >> 1) * 16, wn = (wv & 1) * 32;
  const int lm = lane & 15, quad = lane >> 4;
  const int sr = tid >> 3, sc8 = (tid & 7) * 8;

  f32x4 acc[2];
  acc[0] = (f32x4)(0.f); acc[1] = (f32x4)(0.f);

  auto loadA = [&](int k0) -> uint4 {
    return *(const uint4*)&A[(size_t)(m0 + sr) * K + k0 + sc8];
  };
  auto loadB = [&](int row, int k0) -> uint4 {
    return *(const uint4*)&Bt[(size_t)(n0 + row) * K + k0 + sc8];
  };

  // 2-deep pipeline: loads issued 2 k-iterations before consumption
  uint4 aC = loadA(0), b0C = loadB(sr, 0), b1C = loadB(sr + 32, 0);
  const int k1 = (64 < K) ? 64 : 0;
  uint4 aN = loadA(k1), b0N = loadB(sr, k1), b1N = loadB(sr + 32, k1);

  for (int k0 = 0; k0 < K; k0 += 64) {
    const int kn = (k0 + 128 < K) ? k0 + 128 : k0;  // clamped tail reload
    uint4 aT = loadA(kn), b0T = loadB(sr, kn), b1T = loadB(sr + 32, kn);
    barrier_lds();  // prev ds_reads done; vm prefetches stay in flight
    *(uint4*)&As[sr][sc8] = aC;
    *(uint4*)&Bs[sr][sc8] = b0C;
    *(uint4*)&Bs[sr + 32][sc8] = b1C;
    barrier_lds();
#pragma unroll
    for (int kk = 0; kk < 64; kk += 32) {
      bf16x8 a = *(const bf16x8*)&As[wm + lm][kk + quad * 8];
      bf16x8 b0 = *(const bf16x8*)&Bs[wn + lm][kk + quad * 8];
      bf16x8 b1 = *(const bf16x8*)&Bs[wn + 16 + lm][kk + quad * 8];
      acc[0] = __builtin_amdgcn_mfma_f32_16x16x32_bf16(a, b0, acc[0], 0, 0, 0);
      acc[1] = __builtin_amdgcn_mfma_f32_16x16x32_bf16(a, b1, acc[1], 0, 0, 0);
    }
    aC = aN; b0C = b0N; b1C = b1N;
    aN = aT; b0N = b0T; b1N = b1T;
  }
#pragma unroll
  for (int nt = 0; nt < 2; ++nt) {
    int col = n0 + wn + nt * 16 + lm;
    float bv = (flags & 1) ? bias[col] : 0.f;
#pragma unroll
    for (int t = 0; t < 4; ++t) {
      int row = m0 + wm + quad * 4 + t;
      float v = acc[nt][t] + bv;
      if (flags & 2) v = fmaxf(v, 0.f);
      if (flags & 4) Cb[(size_t)row * N + col] = f2bf(v);
      else C[(size_t)row * N + col] = v;
    }
  }
}

__global__ __launch_bounds__(256) void k_gemm_mfma(const ushort_t* __restrict__ A,
                                                   const ushort_t* __restrict__ Bt,
                                                   const float* __restrict__ bias,
                                                   float* __restrict__ C,
                                                   ushort_t* __restrict__ Cb,
                                                   int N, int K, int flags) {
  gemm32x64_body(A, Bt, bias, C, Cb, N, K, flags, blockIdx.y * 32, blockIdx.x * 64);
}

// merged QKV + Wr GEMMs (independent, same shape family) in one dispatch
__global__ __launch_bounds__(256) void k_gemm_qkvwr(const ushort_t* __restrict__ wb,
                                                    const ushort_t* __restrict__ posb,
                                                    const ushort_t* __restrict__ qkvT,
                                                    const ushort_t* __restrict__ wrT,
                                                    ushort_t* __restrict__ qkvb,
                                                    ushort_t* __restrict__ rbg) {
  const int bx = blockIdx.x;
  if (bx < 24)
    gemm32x64_body(wb, qkvT, nullptr, nullptr, qkvb, QKV_N, DM, 4,
                   blockIdx.y * 32, bx * 64);
  else
    gemm32x64_body(posb, wrT, nullptr, nullptr, rbg, DM, DM, 4,
                   blockIdx.y * 32, (bx - 24) * 64);
}

// ------- MFMA flash attention, split-j partials (flash split-K style) -----
__global__ __launch_bounds__(256) void k_attn(const ushort_t* __restrict__ qkv,
                                              const ushort_t* __restrict__ r,
                                              const float* __restrict__ rwb,
                                              const float* __restrict__ rrb,
                                              float* __restrict__ mlP,
                                              ushort_t* __restrict__ opP) {
  const int h = blockIdx.y;
  const int qt = 64 - blockIdx.x;  // heavy q-tiles dispatch first
  const int c = blockIdx.z;
  if (c > qt) return;  // empty chunk
  const int i0 = qt * 32;
  const int tid = threadIdx.x;
  const int lane = tid & 63, wv = tid >> 6;
  const int lm = lane & 15, quad = lane >> 4;

  __shared__ short qw[32][72];     // (q+rwb) bf16 [i][d]
  __shared__ short qr[33][72];     // (q+rrb) bf16 [i][d]
  __shared__ short ks_[32][72];    // K tile [j][d]
  __shared__ short vsT[64][70];    // V^T [d][j]
  __shared__ short rband[64][72];  // r band [t][d], kidx = kb + t
  __shared__ short pb[32][40];     // P bf16 [i][j]
  __shared__ float rm[14][68];     // r rows 0..13 fp32 (mem-block wrap)
  __shared__ float st[32][33];     // AC fp32 [i][j]
  __shared__ float bdf[32][66];    // BDfull fp32 [i][t]
  __shared__ float m_s[32], l_s[32], alpha_s[32];

  const uint4 zero4 = make_uint4(0, 0, 0, 0);
  const int krr = tid >> 3, kc8 = (tid & 7) * 8;  // K/rband staging coords
  const int vrr = tid >> 4, vc4 = tid & 15;       // V staging coords
  const int kb0 = TT - 32 - i0;

  auto loadK = [&](int j0) -> uint4 {
    return *(const uint4*)&qkv[(size_t)(j0 + krr) * QKV_N + DM + h * DH + kc8];
  };
  auto loadBand = [&](int kidx) -> uint4 {
    return (kidx < TT) ? *(const uint4*)&r[(size_t)kidx * DM + h * DH + kc8]
                       : zero4;
  };

  {  // stage qw/qr with bias add
    int rr = tid >> 3, c8 = (tid & 7) * 8;
    uint4 qv = *(const uint4*)&qkv[(size_t)(i0 + rr) * QKV_N + h * DH + c8];
    float f[8]; unpack8(qv, f);
    float4 w0 = *(const float4*)&rwb[h * DH + c8];
    float4 w1 = *(const float4*)&rwb[h * DH + c8 + 4];
    float4 r0 = *(const float4*)&rrb[h * DH + c8];
    float4 r1 = *(const float4*)&rrb[h * DH + c8 + 4];
    uint4 ow, orr;
    ow.x = pack2(f2bf(f[0] + w0.x), f2bf(f[1] + w0.y));
    ow.y = pack2(f2bf(f[2] + w0.z), f2bf(f[3] + w0.w));
    ow.z = pack2(f2bf(f[4] + w1.x), f2bf(f[5] + w1.y));
    ow.w = pack2(f2bf(f[6] + w1.z), f2bf(f[7] + w1.w));
    orr.x = pack2(f2bf(f[0] + r0.x), f2bf(f[1] + r0.y));
    orr.y = pack2(f2bf(f[2] + r0.z), f2bf(f[3] + r0.w));
    orr.z = pack2(f2bf(f[4] + r1.x), f2bf(f[5] + r1.y));
    orr.w = pack2(f2bf(f[6] + r1.z), f2bf(f[7] + r1.w));
    *(uint4*)&qw[rr][c8] = ow;
    *(uint4*)&qr[rr][c8] = orr;
  }
  if (tid < 112) {  // rm staging (fp32)
    int rr = tid >> 3, c8 = (tid & 7) * 8;
    uint4 v = *(const uint4*)&r[(size_t)rr * DM + h * DH + c8];
    float f[8]; unpack8(v, f);
#pragma unroll
    for (int j = 0; j < 8; ++j) rm[rr][c8 + j] = f[j];
  }
  if (tid < 32) { m_s[tid] = -INFINITY; l_s[tid] = 0.f; }

  f32x4 oA = (f32x4)(0.f);  // O^T accum, d-tile=wv, i = i0+lm
  f32x4 oB = (f32x4)(0.f);  // i = i0+16+lm

  // ---- pipeline prologue: first chunk tile into registers ----
  uint4 kcur = loadK(c * 32);
  const ushort_t* vp0 = &qkv[(size_t)(c * 32 + 2 * vrr) * QKV_N + 2 * DM + h * DH + vc4 * 4];
  uint2 v0cur = *(const uint2*)vp0, v1cur = *(const uint2*)(vp0 + QKV_N);
  uint4 band0cur = loadBand(kb0 + 32 * c + krr);
  uint4 band1cur = loadBand(kb0 + 32 * c + 32 + krr);

  for (int jt = c; jt <= qt; jt += SPLIT) {
    const int j0 = jt * 32;
    // ---- issue next tile's loads (clamped reload on last iteration) ----
    const int jn = (jt + SPLIT <= qt) ? jt + SPLIT : jt;
    uint4 knext = loadK(jn * 32);
    const ushort_t* vpn = &qkv[(size_t)(jn * 32 + 2 * vrr) * QKV_N + 2 * DM + h * DH + vc4 * 4];
    uint2 v0n = *(const uint2*)vpn, v1n = *(const uint2*)(vpn + QKV_N);
    uint4 b0n = loadBand(kb0 + 32 * jn + krr);
    uint4 b1n = loadBand(kb0 + 32 * jn + 32 + krr);

    barrier_lds();  // prior iteration's ds ops done; vmcnt stays in flight
    // ---- write current tile (loaded last iteration) to LDS ----
    *(uint4*)&ks_[krr][kc8] = kcur;
    {
      ushort_t a0 = (ushort_t)(v0cur.x & 0xffffu), a1 = (ushort_t)(v0cur.x >> 16);
      ushort_t a2 = (ushort_t)(v0cur.y & 0xffffu), a3 = (ushort_t)(v0cur.y >> 16);
      ushort_t c0 = (ushort_t)(v1cur.x & 0xffffu), c1 = (ushort_t)(v1cur.x >> 16);
      ushort_t c2 = (ushort_t)(v1cur.y & 0xffffu), c3 = (ushort_t)(v1cur.y >> 16);
      *(unsigned int*)&vsT[vc4 * 4 + 0][2 * vrr] = pack2(a0, c0);
      *(unsigned int*)&vsT[vc4 * 4 + 1][2 * vrr] = pack2(a1, c1);
      *(unsigned int*)&vsT[vc4 * 4 + 2][2 * vrr] = pack2(a2, c2);
      *(unsigned int*)&vsT[vc4 * 4 + 3][2 * vrr] = pack2(a3, c3);
    }
    *(uint4*)&rband[krr][kc8] = band0cur;
    *(uint4*)&rband[krr + 32][kc8] = band1cur;
    barrier_lds();

    {  // ---- phase B: AC + BDfull MFMAs -> LDS ----
      const int acit = wv >> 1, acjt = wv & 1;
      f32x4 ac = (f32x4)(0.f);
#pragma unroll
      for (int k2 = 0; k2 < 64; k2 += 32) {
        bf16x8 a = *(const bf16x8*)&qw[acit * 16 + lm][k2 + quad * 8];
        bf16x8 b = *(const bf16x8*)&ks_[acjt * 16 + lm][k2 + quad * 8];
        ac = __builtin_amdgcn_mfma_f32_16x16x32_bf16(a, b, ac, 0, 0, 0);
      }
#pragma unroll
      for (int t = 0; t < 4; ++t)
        st[acit * 16 + quad * 4 + t][acjt * 16 + lm] = ac[t];

      const int brt = wv >> 1, bc0 = wv & 1, bc1 = (wv & 1) + 2;
      f32x4 bd0 = (f32x4)(0.f), bd1 = (f32x4)(0.f);
#pragma unroll
      for (int k2 = 0; k2 < 64; k2 += 32) {
        bf16x8 a = *(const bf16x8*)&qr[brt * 16 + lm][k2 + quad * 8];
        bf16x8 b0 = *(const bf16x8*)&rband[bc0 * 16 + lm][k2 + quad * 8];
        bf16x8 b1 = *(const bf16x8*)&rband[bc1 * 16 + lm][k2 + quad * 8];
        bd0 = __builtin_amdgcn_mfma_f32_16x16x32_bf16(a, b0, bd0, 0, 0, 0);
        bd1 = __builtin_amdgcn_mfma_f32_16x16x32_bf16(a, b1, bd1, 0, 0, 0);
      }
#pragma unroll
      for (int t = 0; t < 4; ++t) {
        bdf[brt * 16 + quad * 4 + t][bc0 * 16 + lm] = bd0[t];
        bdf[brt * 16 + quad * 4 + t][bc1 * 16 + lm] = bd1[t];
      }
    }
    barrier_lds();

    {  // ---- phase C: score assembly + online softmax ----
      const int ii = tid >> 3, g = tid & 7, jjb = g * 4;
      const int i = i0 + ii;
      float sreg[4];
#pragma unroll
      for (int u = 0; u < 4; ++u) {
        int j = j0 + jjb + u;
        float acv = st[ii][jjb + u];
        float s;
        if (j <= i) {
          s = (acv + bdf[ii][jjb + u - ii + 31]) * ATT_SCALE;
        } else {
          bool inmem = (i < NMTOK && j < NMTOK) ||
                       (i >= TT - NMTOK && j >= TT - NMTOK);
          if (!inmem) s = -1e30f;
          else if (j == i + 1) s = acv * ATT_SCALE;  // rel_shift zero-pad entry
          else {
            float b2 = 0.f;
            const int rrow = j - i - 2;
            for (int d = 0; d < 64; ++d)
              b2 += bfbits2f(((unsigned int)(ushort_t)qr[ii + 1][d]) << 16) *
                    rm[rrow][d];
            s = (acv + b2) * ATT_SCALE;
          }
        }
        sreg[u] = s;
      }
      float tmax = fmaxf(fmaxf(sreg[0], sreg[1]), fmaxf(sreg[2], sreg[3]));
#pragma unroll
      for (int off = 1; off < 8; off <<= 1) tmax = fmaxf(tmax, __shfl_xor(tmax, off));
      const float mold = m_s[ii];
      const float mnew = fmaxf(mold, tmax);
      const float alpha = __expf(mold - mnew);
      float p[4], psum = 0.f;
#pragma unroll
      for (int u = 0; u < 4; ++u) { p[u] = __expf(sreg[u] - mnew); psum += p[u]; }
#pragma unroll
      for (int off = 1; off < 8; off <<= 1) psum += __shfl_xor(psum, off);
      uint2 pk;
      pk.x = pack2(f2bf(p[0]), f2bf(p[1]));
      pk.y = pack2(f2bf(p[2]), f2bf(p[3]));
      *(uint2*)&pb[ii][jjb] = pk;
      if (g == 0) {
        m_s[ii] = mnew;
        l_s[ii] = l_s[ii] * alpha + psum;
        alpha_s[ii] = alpha;
      }
    }
    barrier_lds();

    {  // ---- phase D: O^T = O^T*alpha + V^T P^T ----
      float a0 = alpha_s[lm], a1 = alpha_s[16 + lm];
      union { bf16x8 v; unsigned int u[4]; } av;
      const unsigned int* vp = (const unsigned int*)&vsT[wv * 16 + lm][quad * 8];
      av.u[0] = vp[0]; av.u[1] = vp[1]; av.u[2] = vp[2]; av.u[3] = vp[3];
      bf16x8 p0 = *(const bf16x8*)&pb[lm][quad * 8];
      bf16x8 p1 = *(const bf16x8*)&pb[16 + lm][quad * 8];
#pragma unroll
      for (int t = 0; t < 4; ++t) { oA[t] *= a0; oB[t] *= a1; }
      oA = __builtin_amdgcn_mfma_f32_16x16x32_bf16(av.v, p0, oA, 0, 0, 0);
      oB = __builtin_amdgcn_mfma_f32_16x16x32_bf16(av.v, p1, oB, 0, 0, 0);
    }
    kcur = knext; v0cur = v0n; v1cur = v1n; band0cur = b0n; band1cur = b1n;
  }

  {  // write partials: m, l (fp32) and un-normalized O (bf16, [i][d] layout)
    const int pidx = (qt * NH + h) * SPLIT + c;
    if (tid < 32) {
      mlP[(size_t)pidx * 64 + tid] = m_s[tid];
      mlP[(size_t)pidx * 64 + 32 + tid] = l_s[tid];
    }
    ushort_t o0[4], o1[4];
#pragma unroll
    for (int t = 0; t < 4; ++t) { o0[t] = f2bf(oA[t]); o1[t] = f2bf(oB[t]); }
    size_t ob = (size_t)pidx * 2048;
    *(uint2*)&opP[ob + (size_t)lm * 64 + wv * 16 + quad * 4] = *(uint2*)o0;
    *(uint2*)&opP[ob + (size_t)(16 + lm) * 64 + wv * 16 + quad * 4] = *(uint2*)o1;
  }
}

// -------- combine <=SPLIT chunk partials -> normalized attn output --------
__global__ __launch_bounds__(256) void k_attn_combine(const float* __restrict__ mlP,
                                                      const ushort_t* __restrict__ opP,
                                                      ushort_t* __restrict__ attnb) {
  const int qt = blockIdx.x, h = blockIdx.y;
  const int nc = (qt + 1 < SPLIT) ? qt + 1 : SPLIT;
  const int tid = threadIdx.x;
  const int i = tid >> 3, d8 = (tid & 7) * 8;
  const size_t base = (size_t)(qt * NH + h) * SPLIT;
  float m[SPLIT], l[SPLIT], wgt[SPLIT];
  float M = -INFINITY;
  for (int cc = 0; cc < nc; ++cc) {
    m[cc] = mlP[(base + cc) * 64 + i];
    l[cc] = mlP[(base + cc) * 64 + 32 + i];
    M = fmaxf(M, m[cc]);
  }
  float L = 0.f;
  for (int cc = 0; cc < nc; ++cc) { wgt[cc] = __expf(m[cc] - M); L += l[cc] * wgt[cc]; }
  float acc[8] = {0, 0, 0, 0, 0, 0, 0, 0};
  for (int cc = 0; cc < nc; ++cc) {
    uint4 v = *(const uint4*)&opP[(base + cc) * 2048 + (size_t)i * 64 + d8];
    float f[8]; unpack8(v, f);
#pragma unroll
    for (int k = 0; k < 8; ++k) acc[k] += wgt[cc] * f[k];
  }
  const float inv = 1.f / L;
  ushort_t o8[8];
#pragma unroll
  for (int k = 0; k < 8; ++k) o8[k] = f2bf(acc[k] * inv);
  *(uint4*)&attnb[(size_t)(qt * 32 + i) * DM + h * DH + d8] = *(uint4*)o8;
}

// -------- w' = LayerNorm(w + delta) * g + b; fp32 -> wout, bf16 -> wb -----
__global__ __launch_bounds__(256) void k_addln(const float* __restrict__ w,
                                               float* __restrict__ wout,
                                               ushort_t* __restrict__ wb,
                                               const float* __restrict__ delta,
                                               const float* __restrict__ gamma,
                                               const float* __restrict__ beta) {
  const int row = blockIdx.x;
  const int tid = threadIdx.x;
  __shared__ float red[4], red2[4];
  size_t base = (size_t)row * DM;
  float x0 = w[base + tid] + delta[base + tid];
  float x1 = w[base + tid + 256] + delta[base + tid + 256];
  float s = x0 + x1;
#pragma unroll
  for (int off = 1; off < 64; off <<= 1) s += __shfl_xor(s, off);
  if ((tid & 63) == 0) red[tid >> 6] = s;
  __syncthreads();
  float mu = (red[0] + red[1] + red[2] + red[3]) * (1.f / 512.f);
  float d0 = x0 - mu, d1 = x1 - mu;
  float v = d0 * d0 + d1 * d1;
#pragma unroll
  for (int off = 1; off < 64; off <<= 1) v += __shfl_xor(v, off);
  if ((tid & 63) == 0) red2[tid >> 6] = v;
  __syncthreads();
  float var = (red2[0] + red2[1] + red2[2] + red2[3]) * (1.f / 512.f);
  float rstd = rsqrtf(var + 1e-5f);
  float o0 = d0 * rstd * gamma[tid] + beta[tid];
  float o1 = d1 * rstd * gamma[tid + 256] + beta[tid + 256];
  wout[base + tid] = o0;
  wout[base + tid + 256] = o1;
  wb[base + tid] = f2bf(o0);
  wb[base + tid + 256] = f2bf(o1);
}

extern "C" void kernel_launch(void* const* d_in, const int* in_sizes, int n_in,
                              void* d_out, int out_size, void* d_ws, size_t ws_size,
                              hipStream_t stream) {
  const float* we   = (const float*)d_in[0];
  const float* mem  = (const float*)d_in[1];
  const float* Wqkv = (const float*)d_in[2];
  const float* Wr   = (const float*)d_in[3];
  const float* Wo   = (const float*)d_in[4];
  const float* ln1s = (const float*)d_in[5];
  const float* ln1b = (const float*)d_in[6];
  const float* W1   = (const float*)d_in[7];
  const float* b1   = (const float*)d_in[8];
  const float* W2   = (const float*)d_in[9];
  const float* b2   = (const float*)d_in[10];
  const float* ln2s = (const float*)d_in[11];
  const float* ln2b = (const float*)d_in[12];
  const float* rwb  = (const float*)d_in[13];
  const float* rrb  = (const float*)d_in[14];

  // ---- workspace layout (~76 MB) ----
  float* w     = (float*)d_ws;                        // TT*DM fp32
  float* proj  = w + (size_t)TT * DM;                 // TT*DM fp32 (ff2 overlays)
  ushort_t* wb    = (ushort_t*)(proj + (size_t)TT * DM);  // TT*DM bf16
  ushort_t* posb  = wb + (size_t)TT * DM;             // TT*DM bf16
  ushort_t* attnb = posb + (size_t)TT * DM;           // TT*DM bf16
  ushort_t* qkvb  = attnb + (size_t)TT * DM;          // TT*1536 bf16
  ushort_t* rbg   = qkvb + (size_t)TT * QKV_N;        // TT*DM bf16
  ushort_t* WtAll = rbg + (size_t)TT * DM;            // 4 layers x WT_STRIDE shorts
  ushort_t* opP   = WtAll + (size_t)NLAYER * WT_STRIDE;  // 65*8*SPLIT*2048 shorts
  float* mlP   = (float*)(opP + (size_t)65 * 8 * SPLIT * 2048);  // 65*8*SPLIT*64 f32
  ushort_t* ff1b  = qkvb;                             // TT*DI bf16 overlay
  float* ff2   = proj;
  const size_t OFF_QKVT = 0, OFF_WRT = 786432, OFF_WOT = 1048576,
               OFF_W1T = 1310720, OFF_W2T = 2359296;

  // all-layer weight transpose + build in one dispatch
  k_prep<<<13312 + 4160, 256, 0, stream>>>(Wqkv, Wr, Wo, W1, W2, WtAll,
                                           we, mem, w, wb, posb);

  dim3 gQW(32, 65);          // merged QKV (24 n-tiles) + Wr (8 n-tiles)
  dim3 gDM32(DM / 64, 65);   // Wo / W2
  dim3 gDI32(DI / 64, 65);   // W1
  dim3 gA(65, NH, SPLIT);
  dim3 gC(65, NH);

  for (int l = 0; l < NLAYER; ++l) {
    const ushort_t* Wt = WtAll + (size_t)l * WT_STRIDE;
    k_gemm_qkvwr<<<gQW, 256, 0, stream>>>(wb, posb, Wt + OFF_QKVT,
                                          Wt + OFF_WRT, qkvb, rbg);
    k_attn<<<gA, 256, 0, stream>>>(qkvb, rbg, rwb, rrb, mlP, opP);
    k_attn_combine<<<gC, 256, 0, stream>>>(mlP, opP, attnb);
    k_gemm_mfma<<<gDM32, 256, 0, stream>>>(attnb, Wt + OFF_WOT, nullptr, proj, nullptr,
                                           DM, DM, 0);
    k_addln<<<TT, 256, 0, stream>>>(w, w, wb, proj,
                                    ln1s + (size_t)l * DM, ln1b + (size_t)l * DM);
    k_gemm_mfma<<<gDI32, 256, 0, stream>>>(wb, Wt + OFF_W1T, b1 + (size_t)l * DI, nullptr, ff1b,
                                           DI, DM, 1 | 2 | 4);
    k_gemm_mfma<<<gDM32, 256, 0, stream>>>(ff1b, Wt + OFF_W2T, b2 + (size_t)l * DM, ff2, nullptr,
                                           DM, DI, 1);
    // final layer's LN writes the fp32 result straight into d_out
    float* wout = (l == NLAYER - 1) ? (float*)d_out : w;
    k_addln<<<TT, 256, 0, stream>>>(w, wout, wb, ff2,
                                    ln2s + (size_t)l * DM, ln2b + (size_t)l * DM);
  }
}

// Round 10
// 635.632 us; speedup vs baseline: 1.6395x; 1.1484x over previous
//
#include <hip/hip_runtime.h>
#include <hip/hip_bf16.h>
#include <math.h>

#define TT 2080
#define DM 512
#define DI 2048
#define NH 8
#define DH 64
#define NMTOK 16
#define NLAYER 4
#define QKV_N 1536
#define ATT_SCALE 0.125f
#define SPLIT 8
#define WT_STRIDE 3407872   // shorts per layer's transposed-weight block
#define QRP_HEAD 2200640    // shorts per head of packed QR triangle (rowbase(2080))

typedef short bf16x8 __attribute__((ext_vector_type(8)));
typedef float f32x4 __attribute__((ext_vector_type(4)));
typedef unsigned short ushort_t;

__device__ __forceinline__ ushort_t f2bf(float f) {
  __hip_bfloat16 h = __float2bfloat16(f);
  return *reinterpret_cast<ushort_t*>(&h);
}
__device__ __forceinline__ float bfbits2f(unsigned int hi_bits) {
  return __uint_as_float(hi_bits);
}
__device__ __forceinline__ float bf2f(ushort_t u) {
  return bfbits2f(((unsigned int)u) << 16);
}
__device__ __forceinline__ void unpack8(uint4 v, float* f) {
  f[0] = bfbits2f(v.x << 16); f[1] = bfbits2f(v.x & 0xffff0000u);
  f[2] = bfbits2f(v.y << 16); f[3] = bfbits2f(v.y & 0xffff0000u);
  f[4] = bfbits2f(v.z << 16); f[5] = bfbits2f(v.z & 0xffff0000u);
  f[6] = bfbits2f(v.w << 16); f[7] = bfbits2f(v.w & 0xffff0000u);
}
__device__ __forceinline__ unsigned int pack2(ushort_t lo, ushort_t hi) {
  return (unsigned int)lo | ((unsigned int)hi << 16);
}
// Barrier draining LDS ops only — leaves global (vmcnt) loads in flight.
__device__ __forceinline__ void barrier_lds() {
  asm volatile("s_waitcnt lgkmcnt(0)" ::: "memory");
  __builtin_amdgcn_s_barrier();
}
// Packed QR triangle: row i stores width W_i = ceil4(i+17):
//   p in [0, i]   -> BD value for col j = p           (causal part, p == j!)
//   p = i+1+w     -> wrap value qr[i].r[w], w in [0,16)
__device__ __forceinline__ size_t qr_rowbase(int i) {
  int m = i & 3;
  int r = (m == 0) ? 0 : (m == 1) ? 3 : (m == 2) ? 5 : 6;
  return (size_t)i * (i + 33) / 2 + 6 * (i >> 2) + r;
}

// ---- fused prep: all 4 layers' weight transposes + build w/pos ------------
__global__ __launch_bounds__(256) void k_prep(
    const float* __restrict__ Wqkv, const float* __restrict__ Wr,
    const float* __restrict__ Wo, const float* __restrict__ W1,
    const float* __restrict__ W2, ushort_t* __restrict__ dstAll,
    const float* __restrict__ we, const float* __restrict__ mem,
    float* __restrict__ w, ushort_t* __restrict__ wb,
    ushort_t* __restrict__ posb) {
  const int tid = threadIdx.x;
  if (blockIdx.x >= 13312) {  // ---- build ----
    int idx = (blockIdx.x - 13312) * 256 + tid;
    if (idx >= TT * DM) return;
    int t = idx >> 9, d = idx & 511;
    float v;
    if (t < NMTOK) v = mem[t * DM + d];
    else if (t < NMTOK + 2048) v = we[(t - NMTOK) * DM + d];
    else v = mem[(t - (NMTOK + 2048)) * DM + d];
    w[idx] = v;
    wb[idx] = f2bf(v);
    float p = (float)(TT - 1 - t);
    int i2 = d & 255;
    float freq = 1.0f / powf(10000.f, ((float)(2 * i2)) / 512.f);
    float ang = p * freq;
    posb[idx] = f2bf((d < 256) ? sinf(ang) : cosf(ang));
    return;
  }
  // ---- transpose+cast, layer l ----
  __shared__ float tl[32][33];
  const int l = blockIdx.x / 3328;
  int idx = blockIdx.x % 3328;
  const float* src;
  ushort_t* dst = dstAll + (size_t)l * WT_STRIDE;
  int K, N, local;
  if (idx < 768)       { src = Wqkv + (size_t)l * 512 * 1536; K = 512;  N = 1536; local = idx; }
  else if (idx < 1024) { src = Wr   + (size_t)l * 512 * 512;  dst += 786432;  K = 512;  N = 512;  local = idx - 768; }
  else if (idx < 1280) { src = Wo   + (size_t)l * 512 * 512;  dst += 1048576; K = 512;  N = 512;  local = idx - 1024; }
  else if (idx < 2304) { src = W1   + (size_t)l * 512 * 2048; dst += 1310720; K = 512;  N = 2048; local = idx - 1280; }
  else                 { src = W2   + (size_t)l * 2048 * 512; dst += 2359296; K = 2048; N = 512;  local = idx - 2304; }
  const int ntiles = N / 32;
  const int n0 = (local % ntiles) * 32, k0 = (local / ntiles) * 32;
#pragma unroll
  for (int p = 0; p < 4; ++p) {
    int row = (tid >> 5) + 8 * p, col = tid & 31;
    tl[row][col] = src[(size_t)(k0 + row) * N + n0 + col];
  }
  __syncthreads();
#pragma unroll
  for (int p = 0; p < 4; ++p) {
    int n = (tid >> 5) + 8 * p, k = tid & 31;
    dst[(size_t)(n0 + n) * K + k0 + k] = f2bf(tl[k][n]);
  }
}

// -------- bf16 MFMA GEMM body, 32x64 tile, register prefetch --------------
// flags: 1=+bias, 2=relu, 4=bf16 out (else fp32), 8=also write (v+rrb) to qrb
__device__ __forceinline__ void gemm32x64_body(const ushort_t* __restrict__ A,
                                               const ushort_t* __restrict__ Bt,
                                               const float* __restrict__ bias,
                                               float* __restrict__ C,
                                               ushort_t* __restrict__ Cb,
                                               ushort_t* __restrict__ qrb,
                                               const float* __restrict__ rrb,
                                               int N, int K, int flags,
                                               int m0, int n0) {
  __shared__ short As[32][72];
  __shared__ short Bs[64][72];
  const int tid = threadIdx.x;
  const int lane = tid & 63, wv = tid >> 6;
  const int wm = (wv >> 1) * 16, wn = (wv & 1) * 32;
  const int lm = lane & 15, quad = lane >> 4;
  const int sr = tid >> 3, sc8 = (tid & 7) * 8;

  f32x4 acc[2];
  acc[0] = (f32x4)(0.f); acc[1] = (f32x4)(0.f);

  auto loadA = [&](int k0) -> uint4 {
    return *(const uint4*)&A[(size_t)(m0 + sr) * K + k0 + sc8];
  };
  auto loadB = [&](int row, int k0) -> uint4 {
    return *(const uint4*)&Bt[(size_t)(n0 + row) * K + k0 + sc8];
  };

  uint4 aC = loadA(0), b0C = loadB(sr, 0), b1C = loadB(sr + 32, 0);

  for (int k0 = 0; k0 < K; k0 += 64) {
    const int kn = (k0 + 64 < K) ? k0 + 64 : k0;  // clamped tail reload
    uint4 aN = loadA(kn), b0N = loadB(sr, kn), b1N = loadB(sr + 32, kn);
    barrier_lds();  // prev ds_reads done; vm prefetches stay in flight
    *(uint4*)&As[sr][sc8] = aC;
    *(uint4*)&Bs[sr][sc8] = b0C;
    *(uint4*)&Bs[sr + 32][sc8] = b1C;
    barrier_lds();
#pragma unroll
    for (int kk = 0; kk < 64; kk += 32) {
      bf16x8 a = *(const bf16x8*)&As[wm + lm][kk + quad * 8];
      bf16x8 b0 = *(const bf16x8*)&Bs[wn + lm][kk + quad * 8];
      bf16x8 b1 = *(const bf16x8*)&Bs[wn + 16 + lm][kk + quad * 8];
      acc[0] = __builtin_amdgcn_mfma_f32_16x16x32_bf16(a, b0, acc[0], 0, 0, 0);
      acc[1] = __builtin_amdgcn_mfma_f32_16x16x32_bf16(a, b1, acc[1], 0, 0, 0);
    }
    aC = aN; b0C = b0N; b1C = b1N;
  }
#pragma unroll
  for (int nt = 0; nt < 2; ++nt) {
    int col = n0 + wn + nt * 16 + lm;
    float bv = (flags & 1) ? bias[col] : 0.f;
#pragma unroll
    for (int t = 0; t < 4; ++t) {
      int row = m0 + wm + quad * 4 + t;
      float v = acc[nt][t] + bv;
      if (flags & 2) v = fmaxf(v, 0.f);
      if (flags & 4) Cb[(size_t)row * N + col] = f2bf(v);
      else C[(size_t)row * N + col] = v;
      if ((flags & 8) && col < DM)
        qrb[(size_t)row * DM + col] = f2bf(v + rrb[col]);
    }
  }
}

__global__ __launch_bounds__(256) void k_gemm_mfma(const ushort_t* __restrict__ A,
                                                   const ushort_t* __restrict__ Bt,
                                                   const float* __restrict__ bias,
                                                   float* __restrict__ C,
                                                   ushort_t* __restrict__ Cb,
                                                   int N, int K, int flags) {
  gemm32x64_body(A, Bt, bias, C, Cb, nullptr, nullptr, N, K, flags,
                 blockIdx.y * 32, blockIdx.x * 64);
}

// merged QKV + Wr GEMMs; QKV q-part also emits qrb = q + rrb (bf16)
__global__ __launch_bounds__(256) void k_gemm_qkvwr(const ushort_t* __restrict__ wb,
                                                    const ushort_t* __restrict__ posb,
                                                    const ushort_t* __restrict__ qkvT,
                                                    const ushort_t* __restrict__ wrT,
                                                    ushort_t* __restrict__ qkvb,
                                                    ushort_t* __restrict__ rbg,
                                                    ushort_t* __restrict__ qrb,
                                                    const float* __restrict__ rrb) {
  const int bx = blockIdx.x;
  if (bx < 24)
    gemm32x64_body(wb, qkvT, nullptr, nullptr, qkvb, qrb, rrb, QKV_N, DM,
                   (bx < 8) ? (4 | 8) : 4, blockIdx.y * 32, bx * 64);
  else
    gemm32x64_body(posb, wrT, nullptr, nullptr, rbg, nullptr, nullptr, DM, DM, 4,
                   blockIdx.y * 32, (bx - 24) * 64);
}

// ---- QR GEMM: QR[h][i][k] = qr_i . r_k, written as packed causal triangle -
// Only tiles intersecting {k >= TT-1-i} or {k < 16} are computed.
__global__ __launch_bounds__(256) void k_qr(const ushort_t* __restrict__ qrb,
                                            const ushort_t* __restrict__ rbg,
                                            ushort_t* __restrict__ qrp) {
  const int h = blockIdx.z;
  const int m0 = blockIdx.y * 32, n0 = blockIdx.x * 64;
  if (!(n0 == 0 || n0 + 63 >= TT - 32 - m0)) return;
  __shared__ short As[32][72];
  __shared__ short Bs[64][72];
  const int tid = threadIdx.x;
  const int lane = tid & 63, wv = tid >> 6;
  const int wm = (wv >> 1) * 16, wn = (wv & 1) * 32;
  const int lm = lane & 15, quad = lane >> 4;
  const int sr = tid >> 3, sc8 = (tid & 7) * 8;
  const uint4 zero4 = make_uint4(0, 0, 0, 0);

  *(uint4*)&As[sr][sc8] = *(const uint4*)&qrb[(size_t)(m0 + sr) * DM + h * DH + sc8];
  int br0 = n0 + sr, br1 = n0 + sr + 32;
  *(uint4*)&Bs[sr][sc8] =
      (br0 < TT) ? *(const uint4*)&rbg[(size_t)br0 * DM + h * DH + sc8] : zero4;
  *(uint4*)&Bs[sr + 32][sc8] =
      (br1 < TT) ? *(const uint4*)&rbg[(size_t)br1 * DM + h * DH + sc8] : zero4;
  __syncthreads();

  f32x4 acc[2];
  acc[0] = (f32x4)(0.f); acc[1] = (f32x4)(0.f);
#pragma unroll
  for (int kk = 0; kk < 64; kk += 32) {
    bf16x8 a = *(const bf16x8*)&As[wm + lm][kk + quad * 8];
    bf16x8 b0 = *(const bf16x8*)&Bs[wn + lm][kk + quad * 8];
    bf16x8 b1 = *(const bf16x8*)&Bs[wn + 16 + lm][kk + quad * 8];
    acc[0] = __builtin_amdgcn_mfma_f32_16x16x32_bf16(a, b0, acc[0], 0, 0, 0);
    acc[1] = __builtin_amdgcn_mfma_f32_16x16x32_bf16(a, b1, acc[1], 0, 0, 0);
  }
  const size_t hb = (size_t)h * QRP_HEAD;
#pragma unroll
  for (int nt = 0; nt < 2; ++nt) {
    int col = n0 + wn + nt * 16 + lm;
    if (col >= TT) continue;
#pragma unroll
    for (int t = 0; t < 4; ++t) {
      int row = m0 + wm + quad * 4 + t;
      float v = acc[nt][t];
      int p = row + col - (TT - 1);  // packed causal index (== j)
      size_t rb = hb + qr_rowbase(row);
      if (p >= 0) qrp[rb + p] = f2bf(v);
      if (col < 16) qrp[rb + row + 1 + col] = f2bf(v);  // wrap slot
    }
  }
}

// ------- MFMA flash attention, split-j, BD read from packed QR ------------
__global__ __launch_bounds__(256) void k_attn(const ushort_t* __restrict__ qkv,
                                              const ushort_t* __restrict__ qrp,
                                              const float* __restrict__ rwb,
                                              float* __restrict__ mlP,
                                              ushort_t* __restrict__ opP) {
  const int h = blockIdx.y;
  const int qt = 64 - blockIdx.x;  // heavy q-tiles dispatch first
  const int c = blockIdx.z;
  if (c > qt) return;  // empty chunk
  const int i0 = qt * 32;
  const int tid = threadIdx.x;
  const int lane = tid & 63, wv = tid >> 6;
  const int lm = lane & 15, quad = lane >> 4;

  __shared__ short qw[32][72];   // (q+rwb) bf16 [i][d]
  __shared__ short ks_[32][72];  // K tile [j][d]
  __shared__ short vsT[64][70];  // V^T [d][j]
  __shared__ short pb[32][40];   // P bf16 [i][j]
  __shared__ float st[32][33];   // AC fp32 [i][j]
  __shared__ float m_s[32], l_s[32], alpha_s[32];

  const int krr = tid >> 3, kc8 = (tid & 7) * 8;  // K staging coords
  const int vrr = tid >> 4, vc4 = tid & 15;       // V staging coords
  const int ii = tid >> 3, g = tid & 7, jjb = g * 4;
  const int i = i0 + ii;
  const size_t hb = (size_t)h * QRP_HEAD;
  const size_t qrRow = hb + qr_rowbase(i);      // this thread's QR row
  const size_t qrRowW = hb + qr_rowbase(i + 1) + i + 2;  // wrap base (i+1 row)

  auto loadK = [&](int j0) -> uint4 {
    return *(const uint4*)&qkv[(size_t)(j0 + krr) * QKV_N + DM + h * DH + kc8];
  };

  {  // stage qw with rwb bias add
    uint4 qv = *(const uint4*)&qkv[(size_t)(i0 + krr) * QKV_N + h * DH + kc8];
    float f[8]; unpack8(qv, f);
    float4 w0 = *(const float4*)&rwb[h * DH + kc8];
    float4 w1 = *(const float4*)&rwb[h * DH + kc8 + 4];
    uint4 ow;
    ow.x = pack2(f2bf(f[0] + w0.x), f2bf(f[1] + w0.y));
    ow.y = pack2(f2bf(f[2] + w0.z), f2bf(f[3] + w0.w));
    ow.z = pack2(f2bf(f[4] + w1.x), f2bf(f[5] + w1.y));
    ow.w = pack2(f2bf(f[6] + w1.z), f2bf(f[7] + w1.w));
    *(uint4*)&qw[krr][kc8] = ow;
  }
  if (tid < 32) { m_s[tid] = -INFINITY; l_s[tid] = 0.f; }

  f32x4 oA = (f32x4)(0.f);  // O^T accum, d-tile=wv, i = i0+lm
  f32x4 oB = (f32x4)(0.f);  // i = i0+16+lm

  // ---- pipeline prologue: first chunk tile into registers ----
  uint4 kcur = loadK(c * 32);
  const ushort_t* vp0 = &qkv[(size_t)(c * 32 + 2 * vrr) * QKV_N + 2 * DM + h * DH + vc4 * 4];
  uint2 v0cur = *(const uint2*)vp0, v1cur = *(const uint2*)(vp0 + QKV_N);

  for (int jt = c; jt <= qt; jt += SPLIT) {
    const int j0 = jt * 32;
    // current iteration's BD values (packed causal: index == j), 4 bf16
    uint2 qr2 = *(const uint2*)&qrp[qrRow + j0 + jjb];
    // next tile's loads (clamped reload on last iteration)
    const int jn = (jt + SPLIT <= qt) ? jt + SPLIT : jt;
    uint4 knext = loadK(jn * 32);
    const ushort_t* vpn = &qkv[(size_t)(jn * 32 + 2 * vrr) * QKV_N + 2 * DM + h * DH + vc4 * 4];
    uint2 v0n = *(const uint2*)vpn, v1n = *(const uint2*)(vpn + QKV_N);

    barrier_lds();  // prior iteration's ds ops done; vmcnt stays in flight
    *(uint4*)&ks_[krr][kc8] = kcur;
    {
      ushort_t a0 = (ushort_t)(v0cur.x & 0xffffu), a1 = (ushort_t)(v0cur.x >> 16);
      ushort_t a2 = (ushort_t)(v0cur.y & 0xffffu), a3 = (ushort_t)(v0cur.y >> 16);
      ushort_t c0 = (ushort_t)(v1cur.x & 0xffffu), c1 = (ushort_t)(v1cur.x >> 16);
      ushort_t c2 = (ushort_t)(v1cur.y & 0xffffu), c3 = (ushort_t)(v1cur.y >> 16);
      *(unsigned int*)&vsT[vc4 * 4 + 0][2 * vrr] = pack2(a0, c0);
      *(unsigned int*)&vsT[vc4 * 4 + 1][2 * vrr] = pack2(a1, c1);
      *(unsigned int*)&vsT[vc4 * 4 + 2][2 * vrr] = pack2(a2, c2);
      *(unsigned int*)&vsT[vc4 * 4 + 3][2 * vrr] = pack2(a3, c3);
    }
    barrier_lds();

    {  // ---- phase B: AC MFMAs -> st ----
      const int acit = wv >> 1, acjt = wv & 1;
      f32x4 ac = (f32x4)(0.f);
#pragma unroll
      for (int k2 = 0; k2 < 64; k2 += 32) {
        bf16x8 a = *(const bf16x8*)&qw[acit * 16 + lm][k2 + quad * 8];
        bf16x8 b = *(const bf16x8*)&ks_[acjt * 16 + lm][k2 + quad * 8];
        ac = __builtin_amdgcn_mfma_f32_16x16x32_bf16(a, b, ac, 0, 0, 0);
      }
#pragma unroll
      for (int t = 0; t < 4; ++t)
        st[acit * 16 + quad * 4 + t][acjt * 16 + lm] = ac[t];
    }
    barrier_lds();

    {  // ---- phase C: score assembly + online softmax ----
      float bd4[4];
      bd4[0] = bf2f((ushort_t)(qr2.x & 0xffffu));
      bd4[1] = bf2f((ushort_t)(qr2.x >> 16));
      bd4[2] = bf2f((ushort_t)(qr2.y & 0xffffu));
      bd4[3] = bf2f((ushort_t)(qr2.y >> 16));
      float sreg[4];
#pragma unroll
      for (int u = 0; u < 4; ++u) {
        int j = j0 + jjb + u;
        float acv = st[ii][jjb + u];
        float s;
        if (j <= i) {
          s = (acv + bd4[u]) * ATT_SCALE;
        } else {
          bool inmem = (i < NMTOK && j < NMTOK) ||
                       (i >= TT - NMTOK && j >= TT - NMTOK);
          if (!inmem) s = -1e30f;
          else if (j == i + 1) s = acv * ATT_SCALE;  // rel_shift zero-pad entry
          else s = (acv + bf2f(qrp[qrRowW + (j - i - 2)])) * ATT_SCALE;  // wrap
        }
        sreg[u] = s;
      }
      float tmax = fmaxf(fmaxf(sreg[0], sreg[1]), fmaxf(sreg[2], sreg[3]));
#pragma unroll
      for (int off = 1; off < 8; off <<= 1) tmax = fmaxf(tmax, __shfl_xor(tmax, off));
      const float mold = m_s[ii];
      const float mnew = fmaxf(mold, tmax);
      const float alpha = __expf(mold - mnew);
      float p[4], psum = 0.f;
#pragma unroll
      for (int u = 0; u < 4; ++u) { p[u] = __expf(sreg[u] - mnew); psum += p[u]; }
#pragma unroll
      for (int off = 1; off < 8; off <<= 1) psum += __shfl_xor(psum, off);
      uint2 pk;
      pk.x = pack2(f2bf(p[0]), f2bf(p[1]));
      pk.y = pack2(f2bf(p[2]), f2bf(p[3]));
      *(uint2*)&pb[ii][jjb] = pk;
      if (g == 0) {
        m_s[ii] = mnew;
        l_s[ii] = l_s[ii] * alpha + psum;
        alpha_s[ii] = alpha;
      }
    }
    barrier_lds();

    {  // ---- phase D: O^T = O^T*alpha + V^T P^T ----
      float a0 = alpha_s[lm], a1 = alpha_s[16 + lm];
      union { bf16x8 v; unsigned int u[4]; } av;
      const unsigned int* vp = (const unsigned int*)&vsT[wv * 16 + lm][quad * 8];
      av.u[0] = vp[0]; av.u[1] = vp[1]; av.u[2] = vp[2]; av.u[3] = vp[3];
      bf16x8 p0 = *(const bf16x8*)&pb[lm][quad * 8];
      bf16x8 p1 = *(const bf16x8*)&pb[16 + lm][quad * 8];
#pragma unroll
      for (int t = 0; t < 4; ++t) { oA[t] *= a0; oB[t] *= a1; }
      oA = __builtin_amdgcn_mfma_f32_16x16x32_bf16(av.v, p0, oA, 0, 0, 0);
      oB = __builtin_amdgcn_mfma_f32_16x16x32_bf16(av.v, p1, oB, 0, 0, 0);
    }
    kcur = knext; v0cur = v0n; v1cur = v1n;
  }

  {  // write partials: m, l (fp32) and un-normalized O (bf16, [i][d] layout)
    const int pidx = (qt * NH + h) * SPLIT + c;
    if (tid < 32) {
      mlP[(size_t)pidx * 64 + tid] = m_s[tid];
      mlP[(size_t)pidx * 64 + 32 + tid] = l_s[tid];
    }
    ushort_t o0[4], o1[4];
#pragma unroll
    for (int t = 0; t < 4; ++t) { o0[t] = f2bf(oA[t]); o1[t] = f2bf(oB[t]); }
    size_t ob = (size_t)pidx * 2048;
    *(uint2*)&opP[ob + (size_t)lm * 64 + wv * 16 + quad * 4] = *(uint2*)o0;
    *(uint2*)&opP[ob + (size_t)(16 + lm) * 64 + wv * 16 + quad * 4] = *(uint2*)o1;
  }
}

// -------- combine <=SPLIT chunk partials -> normalized attn output --------
__global__ __launch_bounds__(256) void k_attn_combine(const float* __restrict__ mlP,
                                                      const ushort_t* __restrict__ opP,
                                                      ushort_t* __restrict__ attnb) {
  const int qt = blockIdx.x, h = blockIdx.y;
  const int nc = (qt + 1 < SPLIT) ? qt + 1 : SPLIT;
  const int tid = threadIdx.x;
  const int i = tid >> 3, d8 = (tid & 7) * 8;
  const size_t base = (size_t)(qt * NH + h) * SPLIT;
  float m[SPLIT], l[SPLIT], wgt[SPLIT];
  float M = -INFINITY;
  for (int cc = 0; cc < nc; ++cc) {
    m[cc] = mlP[(base + cc) * 64 + i];
    l[cc] = mlP[(base + cc) * 64 + 32 + i];
    M = fmaxf(M, m[cc]);
  }
  float L = 0.f;
  for (int cc = 0; cc < nc; ++cc) { wgt[cc] = __expf(m[cc] - M); L += l[cc] * wgt[cc]; }
  float acc[8] = {0, 0, 0, 0, 0, 0, 0, 0};
  for (int cc = 0; cc < nc; ++cc) {
    uint4 v = *(const uint4*)&opP[(base + cc) * 2048 + (size_t)i * 64 + d8];
    float f[8]; unpack8(v, f);
#pragma unroll
    for (int k = 0; k < 8; ++k) acc[k] += wgt[cc] * f[k];
  }
  const float inv = 1.f / L;
  ushort_t o8[8];
#pragma unroll
  for (int k = 0; k < 8; ++k) o8[k] = f2bf(acc[k] * inv);
  *(uint4*)&attnb[(size_t)(qt * 32 + i) * DM + h * DH + d8] = *(uint4*)o8;
}

// -------- w' = LayerNorm(w + delta) * g + b; fp32 -> wout, bf16 -> wb -----
__global__ __launch_bounds__(256) void k_addln(const float* __restrict__ w,
                                               float* __restrict__ wout,
                                               ushort_t* __restrict__ wb,
                                               const float* __restrict__ delta,
                                               const float* __restrict__ gamma,
                                               const float* __restrict__ beta) {
  const int row = blockIdx.x;
  const int tid = threadIdx.x;
  __shared__ float red[4], red2[4];
  size_t base = (size_t)row * DM;
  float x0 = w[base + tid] + delta[base + tid];
  float x1 = w[base + tid + 256] + delta[base + tid + 256];
  float s = x0 + x1;
#pragma unroll
  for (int off = 1; off < 64; off <<= 1) s += __shfl_xor(s, off);
  if ((tid & 63) == 0) red[tid >> 6] = s;
  __syncthreads();
  float mu = (red[0] + red[1] + red[2] + red[3]) * (1.f / 512.f);
  float d0 = x0 - mu, d1 = x1 - mu;
  float v = d0 * d0 + d1 * d1;
#pragma unroll
  for (int off = 1; off < 64; off <<= 1) v += __shfl_xor(v, off);
  if ((tid & 63) == 0) red2[tid >> 6] = v;
  __syncthreads();
  float var = (red2[0] + red2[1] + red2[2] + red2[3]) * (1.f / 512.f);
  float rstd = rsqrtf(var + 1e-5f);
  float o0 = d0 * rstd * gamma[tid] + beta[tid];
  float o1 = d1 * rstd * gamma[tid + 256] + beta[tid + 256];
  wout[base + tid] = o0;
  wout[base + tid + 256] = o1;
  wb[base + tid] = f2bf(o0);
  wb[base + tid + 256] = f2bf(o1);
}

extern "C" void kernel_launch(void* const* d_in, const int* in_sizes, int n_in,
                              void* d_out, int out_size, void* d_ws, size_t ws_size,
                              hipStream_t stream) {
  const float* we   = (const float*)d_in[0];
  const float* mem  = (const float*)d_in[1];
  const float* Wqkv = (const float*)d_in[2];
  const float* Wr   = (const float*)d_in[3];
  const float* Wo   = (const float*)d_in[4];
  const float* ln1s = (const float*)d_in[5];
  const float* ln1b = (const float*)d_in[6];
  const float* W1   = (const float*)d_in[7];
  const float* b1   = (const float*)d_in[8];
  const float* W2   = (const float*)d_in[9];
  const float* b2   = (const float*)d_in[10];
  const float* ln2s = (const float*)d_in[11];
  const float* ln2b = (const float*)d_in[12];
  const float* rwb  = (const float*)d_in[13];
  const float* rrb  = (const float*)d_in[14];

  // ---- workspace layout (~113 MB) ----
  float* w     = (float*)d_ws;                        // TT*DM fp32
  float* proj  = w + (size_t)TT * DM;                 // TT*DM fp32 (ff2 overlays)
  ushort_t* wb    = (ushort_t*)(proj + (size_t)TT * DM);  // TT*DM bf16
  ushort_t* posb  = wb + (size_t)TT * DM;             // TT*DM bf16
  ushort_t* attnb = posb + (size_t)TT * DM;           // TT*DM bf16
  ushort_t* qkvb  = attnb + (size_t)TT * DM;          // TT*1536 bf16
  ushort_t* rbg   = qkvb + (size_t)TT * QKV_N;        // TT*DM bf16
  ushort_t* WtAll = rbg + (size_t)TT * DM;            // 4 layers x WT_STRIDE shorts
  ushort_t* opP   = WtAll + (size_t)NLAYER * WT_STRIDE;  // 65*8*SPLIT*2048 shorts
  float* mlP   = (float*)(opP + (size_t)65 * 8 * SPLIT * 2048);  // 65*8*SPLIT*64 f32
  ushort_t* qrb  = (ushort_t*)(mlP + (size_t)65 * 8 * SPLIT * 64);  // TT*DM bf16
  ushort_t* qrp  = qrb + (size_t)TT * DM;             // NH * QRP_HEAD shorts
  ushort_t* ff1b  = qkvb;                             // TT*DI bf16 overlay
  float* ff2   = proj;
  const size_t OFF_QKVT = 0, OFF_WRT = 786432, OFF_WOT = 1048576,
               OFF_W1T = 1310720, OFF_W2T = 2359296;

  // all-layer weight transpose + build in one dispatch
  k_prep<<<13312 + 4160, 256, 0, stream>>>(Wqkv, Wr, Wo, W1, W2, WtAll,
                                           we, mem, w, wb, posb);

  dim3 gQW(32, 65);          // merged QKV (24 n-tiles) + Wr (8 n-tiles)
  dim3 gDM32(DM / 64, 65);   // Wo / W2
  dim3 gDI32(DI / 64, 65);   // W1
  dim3 gQR(33, 65, NH);
  dim3 gA(65, NH, SPLIT);
  dim3 gC(65, NH);

  for (int l = 0; l < NLAYER; ++l) {
    const ushort_t* Wt = WtAll + (size_t)l * WT_STRIDE;
    k_gemm_qkvwr<<<gQW, 256, 0, stream>>>(wb, posb, Wt + OFF_QKVT,
                                          Wt + OFF_WRT, qkvb, rbg, qrb, rrb);
    k_qr<<<gQR, 256, 0, stream>>>(qrb, rbg, qrp);
    k_attn<<<gA, 256, 0, stream>>>(qkvb, qrp, rwb, mlP, opP);
    k_attn_combine<<<gC, 256, 0, stream>>>(mlP, opP, attnb);
    k_gemm_mfma<<<gDM32, 256, 0, stream>>>(attnb, Wt + OFF_WOT, nullptr, proj, nullptr,
                                           DM, DM, 0);
    k_addln<<<TT, 256, 0, stream>>>(w, w, wb, proj,
                                    ln1s + (size_t)l * DM, ln1b + (size_t)l * DM);
    k_gemm_mfma<<<gDI32, 256, 0, stream>>>(wb, Wt + OFF_W1T, b1 + (size_t)l * DI, nullptr, ff1b,
                                           DI, DM, 1 | 2 | 4);
    k_gemm_mfma<<<gDM32, 256, 0, stream>>>(ff1b, Wt + OFF_W2T, b2 + (size_t)l * DM, ff2, nullptr,
                                           DM, DI, 1);
    float* wout = (l == NLAYER - 1) ? (float*)d_out : w;
    k_addln<<<TT, 256, 0, stream>>>(w, wout, wb, ff2,
                                    ln2s + (size_t)l * DM, ln2b + (size_t)l * DM);
  }
}